// Round 1
// 593.015 us; speedup vs baseline: 1.2228x; 1.2228x over previous
//
#include <hip/hip_runtime.h>
#include <hip/hip_bf16.h>
#include <cstdint>
#include <cstddef>

#define N_TOK 50176      // B*H*W
#define HWSZ  3136       // 56*56
#define BATCH 16

#define GF_MUL     1
#define GF_ASCALE  2
#define GF_KVSPLIT 4

typedef __hip_bfloat16 bf16;
typedef __attribute__((ext_vector_type(8))) short bf16x8;
typedef __attribute__((ext_vector_type(4))) float f32x4;
typedef __attribute__((ext_vector_type(4))) unsigned short u16x4;

__device__ __forceinline__ void  stf(float* p, size_t i, float v) { p[i] = v; }
__device__ __forceinline__ void  stf(bf16* p, size_t i, float v) { p[i] = __float2bfloat16(v); }
__device__ __forceinline__ float bu2f(unsigned short u) {
    unsigned int x = ((unsigned int)u) << 16; float f; __builtin_memcpy(&f, &x, 4); return f;
}
__device__ __forceinline__ unsigned short f2bu(float f) {
    bf16 t = __float2bfloat16(f); unsigned short u; __builtin_memcpy(&u, &t, 2); return u;
}

// ---------------- batched weight prep: W[K][N] fp32 -> WT[N][K] bf16 (9 mats, 1 launch) ----------------
struct WtrDesc { const float* src; bf16* dst; int K; int N; int off; };
struct WtrPack { WtrDesc d[9]; int total; };
__global__ __launch_bounds__(256) void wtr_all(WtrPack p)
{
    int idx = blockIdx.x * 256 + threadIdx.x;
    if (idx >= p.total) return;
    #pragma unroll
    for (int s = 0; s < 9; s++) {
        int lo = p.d[s].off, hi = lo + p.d[s].K * p.d[s].N;
        if (idx >= lo && idx < hi) {
            int j = idx - lo;
            int k = j / p.d[s].N, n = j % p.d[s].N;
            p.d[s].dst[(size_t)n * p.d[s].K + k] = __float2bfloat16(p.d[s].src[j]);
        }
    }
}

// ---------------- LayerNorm: one wave per row (fp32 in -> bf16 out) ----------------
__global__ __launch_bounds__(256) void ln_kernel(const float* __restrict__ in,
    const float* __restrict__ w, const float* __restrict__ b,
    bf16* __restrict__ out, int rows, int Cdim)
{
    int wave = threadIdx.x >> 6, lane = threadIdx.x & 63;
    int row = blockIdx.x * 4 + wave;
    if (row >= rows) return;
    const float* p = in + (size_t)row * Cdim;
    int nj = Cdim >> 6;
    float v[4];
    float s = 0.f;
    for (int j = 0; j < nj; j++) { v[j] = p[lane + 64 * j]; s += v[j]; }
    for (int off = 32; off; off >>= 1) s += __shfl_xor(s, off, 64);
    float mean = s / (float)Cdim;
    float vs = 0.f;
    for (int j = 0; j < nj; j++) { float d = v[j] - mean; vs += d * d; }
    for (int off = 32; off; off >>= 1) vs += __shfl_xor(vs, off, 64);
    float rstd = 1.f / sqrtf(vs / (float)Cdim + 1e-6f);
    bf16* q = out + (size_t)row * Cdim;
    for (int j = 0; j < nj; j++) {
        int c = lane + 64 * j;
        q[c] = __float2bfloat16((v[j] - mean) * rstd * w[c] + b[c]);
    }
}

// ---------------- MFMA GEMM: C = A[M,K](bf16) @ WT[N,K]^T(bf16) + bias ----------------
// 128x128 tile, BK=32, 256 threads (4 waves 2x2), 16x16x32 MFMA, fp32 accum.
#define LDT 56   // padded LDS K-stride (112B: 16B-aligned, 2-way banks)
template<int FLAGS, typename OT>
__global__ __launch_bounds__(256) void gemm_mfma(
    const bf16* __restrict__ A, int lda,
    const bf16* __restrict__ WT,           // [N][K]
    const float* __restrict__ bias,
    OT* __restrict__ C, int ldc,
    int M, int K, int N,
    const bf16* __restrict__ mul, int mulld,
    const float* __restrict__ ascale,      // [BATCH][K]
    bf16* __restrict__ kout, bf16* __restrict__ vout)
{
    __shared__ bf16 As[128][LDT];
    __shared__ bf16 Bs[128][LDT];
    int ntile = N >> 7;
    int m0 = (blockIdx.x / ntile) * 128;
    int n0 = (blockIdx.x % ntile) * 128;
    int tid = threadIdx.x;
    int lane = tid & 63, wid = tid >> 6;
    int wr = (wid >> 1) * 64, wc = (wid & 1) * 64;
    int lrow = lane & 15, lko = (lane >> 4) * 8;

    f32x4 acc[4][4];
    #pragma unroll
    for (int i = 0; i < 4; i++)
        #pragma unroll
        for (int j = 0; j < 4; j++)
            acc[i][j] = (f32x4){0.f, 0.f, 0.f, 0.f};

    for (int k0 = 0; k0 < K; k0 += 32) {
        #pragma unroll
        for (int i = 0; i < 2; i++) {
            int idx = tid + i * 256;
            int r = idx >> 2, ko = (idx & 3) * 8;
            bf16x8 v = *reinterpret_cast<const bf16x8*>(A + (size_t)(m0 + r) * lda + k0 + ko);
            if (FLAGS & GF_ASCALE) {
                int bidx = (m0 + r) / HWSZ;
                const float* as = ascale + (size_t)bidx * K + k0 + ko;
                #pragma unroll
                for (int e = 0; e < 8; e++)
                    v[e] = (short)f2bu(bu2f((unsigned short)v[e]) * as[e]);
            }
            *reinterpret_cast<bf16x8*>(&As[r][ko]) = v;
            bf16x8 wv = *reinterpret_cast<const bf16x8*>(WT + (size_t)(n0 + r) * K + k0 + ko);
            *reinterpret_cast<bf16x8*>(&Bs[r][ko]) = wv;
        }
        __syncthreads();
        bf16x8 af[4], br[4];
        #pragma unroll
        for (int i = 0; i < 4; i++)
            af[i] = *reinterpret_cast<const bf16x8*>(&As[wr + i * 16 + lrow][lko]);
        #pragma unroll
        for (int j = 0; j < 4; j++)
            br[j] = *reinterpret_cast<const bf16x8*>(&Bs[wc + j * 16 + lrow][lko]);
        #pragma unroll
        for (int i = 0; i < 4; i++)
            #pragma unroll
            for (int j = 0; j < 4; j++)
                acc[i][j] = __builtin_amdgcn_mfma_f32_16x16x32_bf16(af[i], br[j], acc[i][j], 0, 0, 0);
        __syncthreads();
    }

    int orow = (lane >> 4) * 4;
    int ocol = lane & 15;
    #pragma unroll
    for (int i = 0; i < 4; i++) {
        #pragma unroll
        for (int j = 0; j < 4; j++) {
            #pragma unroll
            for (int p = 0; p < 4; p++) {
                int gm = m0 + wr + i * 16 + orow + p;
                int gn = n0 + wc + j * 16 + ocol;
                float v = acc[i][j][p] + bias[gn];
                if (FLAGS & GF_KVSPLIT) {
                    int bb = gm / HWSZ, n = gm % HWSZ;
                    if (gn < 128)
                        kout[(((size_t)bb * 8 + (gn >> 4)) * HWSZ + n) * 16 + (gn & 15)] = __float2bfloat16(v);
                    else
                        vout[(((size_t)bb * 8 + ((gn - 128) >> 4)) * HWSZ + n) * 16 + ((gn - 128) & 15)] = __float2bfloat16(v);
                } else {
                    if (FLAGS & GF_MUL) v *= __bfloat162float(mul[(size_t)gm * mulld + gn]);
                    stf(C, (size_t)gm * ldc + gn, v);
                }
            }
        }
    }
}

// ---------------- fp32 vector GEMM (small q projection only) ----------------
__global__ __launch_bounds__(256) void gemm_k(
    const float* __restrict__ A, int lda,
    const float* __restrict__ Wt, const float* __restrict__ bias,
    float* __restrict__ Cc, int ldc, int M, int K, int Nc)
{
    __shared__ float As[16][68];
    __shared__ float Ws[16][64];
    int ntile = Nc >> 6;
    int tile_n = blockIdx.x % ntile;
    int tile_m = blockIdx.x / ntile;
    int m0 = tile_m * 64, n0 = tile_n * 64;
    int tid = threadIdx.x;
    int tx = tid & 15, ty = tid >> 4;
    float acc[4][4] = {};
    for (int k0 = 0; k0 < K; k0 += 16) {
        int ks = tid & 15, ms = tid >> 4;
        #pragma unroll
        for (int i = 0; i < 4; i++) {
            int gm = m0 + ms + i * 16;
            As[ks][ms + i * 16] = (gm < M) ? A[(size_t)gm * lda + k0 + ks] : 0.f;
        }
        #pragma unroll
        for (int j = 0; j < 4; j++) {
            int k = (tid >> 6) * 4 + j;
            Ws[k][tid & 63] = Wt[(size_t)(k0 + k) * Nc + n0 + (tid & 63)];
        }
        __syncthreads();
        #pragma unroll
        for (int k = 0; k < 16; k++) {
            float a[4], w[4];
            #pragma unroll
            for (int i = 0; i < 4; i++) a[i] = As[k][ty * 4 + i];
            #pragma unroll
            for (int j = 0; j < 4; j++) w[j] = Ws[k][tx * 4 + j];
            #pragma unroll
            for (int i = 0; i < 4; i++)
                #pragma unroll
                for (int j = 0; j < 4; j++)
                    acc[i][j] += a[i] * w[j];
        }
        __syncthreads();
    }
    #pragma unroll
    for (int i = 0; i < 4; i++) {
        int gm = m0 + ty * 4 + i;
        if (gm >= M) continue;
        #pragma unroll
        for (int j = 0; j < 4; j++) {
            int gn = n0 + tx * 4 + j;
            Cc[(size_t)gm * ldc + gn] = acc[i][j] + bias[gn];
        }
    }
}

// ---------------- LDS-tiled depthwise 7x7 conv ----------------
// Block: 256 threads; tile = 8 rows x 14 cols x 128 ch; LDS holds zero-padded
// (8+6) x (14+6) x 128 input tile (71.7 KB -> 2 blocks/CU).
// Thread: ch8 = tid&15 (8 channels), pos0 = tid>>4; computes 7 outputs
// (pos0 + 16*i) entirely from LDS; weights hoisted per (ky,kx) tap (L1-hot).
#define DW_TX 14
#define DW_TY 8
#define DW_LC 20   // DW_TX + 6
#define DW_LR 14   // DW_TY + 6
__global__ __launch_bounds__(256) void dwconv_tile(const bf16* __restrict__ in,
    bf16* __restrict__ out,
    const float* __restrict__ w0, const float* __restrict__ b0,
    const float* __restrict__ w1, const float* __restrict__ b1, int split)
{
    __shared__ bf16 tile[DW_LR * DW_LC * 128];
    int blk = blockIdx.x;
    int b = blk / 56;
    int r = blk % 56;
    int cc = r & 1, xt = (r >> 1) & 3, yt = r >> 3;   // 2 ch-chunks x 4 x-tiles x 7 y-tiles
    int ch0 = cc * 128;
    int x0 = xt * DW_TX, y0 = yt * DW_TY;
    int tid = threadIdx.x;

    // ---- stage zero-padded tile into LDS ----
    const bf16* base = in + (size_t)b * HWSZ * 256 + ch0;
    for (int idx = tid; idx < DW_LR * DW_LC * 16; idx += 256) {
        int ch8 = idx & 15;
        int pos = idx >> 4;
        int col = pos % DW_LC, row = pos / DW_LC;
        int gy = y0 + row - 3, gx = x0 + col - 3;
        bf16x8 v = {0, 0, 0, 0, 0, 0, 0, 0};
        if (gy >= 0 && gy < 56 && gx >= 0 && gx < 56)
            v = *reinterpret_cast<const bf16x8*>(base + ((size_t)gy * 56 + gx) * 256 + ch8 * 8);
        *reinterpret_cast<bf16x8*>(&tile[(size_t)idx * 8]) = v;
    }
    __syncthreads();

    // ---- weight selection for this 128-ch chunk ----
    const float* wp; const float* bp; int ws, cwt;
    if (ch0 < split) { wp = w0; bp = b0; ws = split;       cwt = ch0; }
    else             { wp = w1; bp = b1; ws = 256 - split; cwt = ch0 - split; }
    int ch8 = tid & 15;
    cwt += ch8 * 8;
    int pos0 = tid >> 4;

    // precompute per-output LDS base offsets (element index)
    int off[7];
    #pragma unroll
    for (int i = 0; i < 7; i++) {
        int p = pos0 + 16 * i;
        int x = p % DW_TX, ry = p / DW_TX;
        off[i] = (ry * DW_LC + x) * 128 + ch8 * 8;
    }
    float acc[7][8];
    #pragma unroll
    for (int i = 0; i < 7; i++)
        #pragma unroll
        for (int e = 0; e < 8; e++) acc[i][e] = 0.f;

    const float* wbase = wp + cwt;
    for (int ky = 0; ky < 7; ky++) {
        const float* wq = wbase + ky * 7 * ws;
        int koff = ky * (DW_LC * 128);
        for (int kx = 0; kx < 7; kx++) {
            float4 wa = *reinterpret_cast<const float4*>(wq);
            float4 wb = *reinterpret_cast<const float4*>(wq + 4);
            #pragma unroll
            for (int i = 0; i < 7; i++) {
                bf16x8 v = *reinterpret_cast<const bf16x8*>(&tile[off[i] + koff]);
                acc[i][0] += bu2f((unsigned short)v[0]) * wa.x;
                acc[i][1] += bu2f((unsigned short)v[1]) * wa.y;
                acc[i][2] += bu2f((unsigned short)v[2]) * wa.z;
                acc[i][3] += bu2f((unsigned short)v[3]) * wa.w;
                acc[i][4] += bu2f((unsigned short)v[4]) * wb.x;
                acc[i][5] += bu2f((unsigned short)v[5]) * wb.y;
                acc[i][6] += bu2f((unsigned short)v[6]) * wb.z;
                acc[i][7] += bu2f((unsigned short)v[7]) * wb.w;
            }
            wq += ws;
            koff += 128;
        }
    }

    // ---- bias + store ----
    float4 ba = *reinterpret_cast<const float4*>(bp + cwt);
    float4 bb = *reinterpret_cast<const float4*>(bp + cwt + 4);
    bf16* obase = out + (size_t)b * HWSZ * 256 + ch0 + ch8 * 8;
    #pragma unroll
    for (int i = 0; i < 7; i++) {
        int p = pos0 + 16 * i;
        int x = p % DW_TX, ry = p / DW_TX;
        size_t gpos = (size_t)(y0 + ry) * 56 + (x0 + x);
        bf16x8 o;
        o[0] = (short)f2bu(acc[i][0] + ba.x);
        o[1] = (short)f2bu(acc[i][1] + ba.y);
        o[2] = (short)f2bu(acc[i][2] + ba.z);
        o[3] = (short)f2bu(acc[i][3] + ba.w);
        o[4] = (short)f2bu(acc[i][4] + bb.x);
        o[5] = (short)f2bu(acc[i][5] + bb.y);
        o[6] = (short)f2bu(acc[i][6] + bb.z);
        o[7] = (short)f2bu(acc[i][7] + bb.w);
        *reinterpret_cast<bf16x8*>(obase + gpos * 256) = o;
    }
}

// ---------------- rgb/t elementwise -> codin[N,256] ----------------
__global__ void rgbt_k(const bf16* __restrict__ rgb, const bf16* __restrict__ t,
                       bf16* __restrict__ codin, int total /* N*128 */)
{
    int i = blockIdx.x * blockDim.x + threadIdx.x;
    if (i >= total) return;
    int n = i >> 7, c = i & 127;
    float a = __bfloat162float(rgb[i]), bb = __bfloat162float(t[i]);
    codin[(size_t)n * 256 + c] = __float2bfloat16(a * bb);
    codin[(size_t)n * 256 + 128 + c] = __float2bfloat16(fabsf(a - bb));
}

// ---------------- cosine-gate partial reductions ----------------
__global__ __launch_bounds__(256) void cosred_k(const bf16* __restrict__ codi,
    float* __restrict__ part)   // [B][64][513]
{
    int b = blockIdx.x >> 4;
    int bi = blockIdx.x & 15;
    int wave = threadIdx.x >> 6, lane = threadIdx.x & 63;
    int slot = bi * 4 + wave;
    float dloc[4] = {0,0,0,0}, n2loc[4] = {0,0,0,0};
    float n1loc = 0.f;
    for (int i = 0; i < 49; i++) {
        int p = slot * 49 + i;
        const bf16* row = codi + ((size_t)b * HWSZ + p) * 256;
        float v[4]; float sum = 0.f;
        #pragma unroll
        for (int j = 0; j < 4; j++) { v[j] = __bfloat162float(row[lane + 64 * j]); sum += v[j]; }
        for (int off = 32; off; off >>= 1) sum += __shfl_xor(sum, off, 64);
        float amap = sum * (1.f / 256.f);
        #pragma unroll
        for (int j = 0; j < 4; j++) { dloc[j] += amap * v[j]; n2loc[j] += v[j] * v[j]; }
        n1loc += amap * amap;
    }
    float* dst = part + ((size_t)b * 64 + slot) * 513;
    #pragma unroll
    for (int j = 0; j < 4; j++) {
        dst[lane + 64 * j] = dloc[j];
        dst[256 + lane + 64 * j] = n2loc[j];
    }
    if (lane == 0) dst[512] = n1loc;
}

// ---------------- cos_sim + MLP + sigmoid -> attn_c[B,256] fp32 ----------------
__global__ __launch_bounds__(256) void mlp_kernel(const float* __restrict__ part,
    const float* __restrict__ fc1w, const float* __restrict__ fc2w,
    float* __restrict__ attnc)
{
    int b = blockIdx.x;
    int tid = threadIdx.x;
    __shared__ float cosb[256];
    __shared__ float hbuf[32];
    const float* pb = part + (size_t)b * 64 * 513;
    float dot = 0.f, n2 = 0.f, n1 = 0.f;
    for (int s = 0; s < 64; s++) {
        dot += pb[s * 513 + tid];
        n2  += pb[s * 513 + 256 + tid];
        n1  += pb[s * 513 + 512];
    }
    float cs = dot / (sqrtf(n1) * sqrtf(n2) + 1e-6f);
    cosb[tid] = cs;
    __syncthreads();
    if (tid < 32) {
        float h = 0.f;
        for (int c = 0; c < 256; c++) h += cosb[c] * fc1w[c * 32 + tid];
        h = 0.5f * h * (1.f + erff(h * 0.70710678f));
        hbuf[tid] = h;
    }
    __syncthreads();
    float o = 0.f;
    for (int j = 0; j < 32; j++) o += hbuf[j] * fc2w[j * 256 + tid];
    attnc[b * 256 + tid] = 1.f / (1.f + expf(-o));
}

// ---------------- 8x8 mean-pool of concat(xn, xen) -> rx_pool[B,49,384] fp32 ----------------
__global__ __launch_bounds__(384) void pool_kernel(const bf16* __restrict__ xn,
    const bf16* __restrict__ xen, float* __restrict__ rxpool)
{
    int bij = blockIdx.x;
    int b = bij / 49; int ij = bij % 49; int i = ij / 7, j = ij % 7;
    int c = threadIdx.x;
    float s = 0.f;
    for (int dy = 0; dy < 8; dy++)
        for (int dx = 0; dx < 8; dx++) {
            size_t n = ((size_t)b * 56 + (i * 8 + dy)) * 56 + (j * 8 + dx);
            s += (c < 256) ? __bfloat162float(xn[n * 256 + c])
                           : __bfloat162float(xen[n * 128 + (c - 256)]);
        }
    rxpool[(size_t)bij * 384 + c] = s * (1.f / 64.f);
}

// ---------------- fused scores->softmax->A@V per (b,h,q), head-major K/V ----------------
__global__ __launch_bounds__(256) void attn_kernel(const float* __restrict__ qbuf,
    const bf16* __restrict__ kbuf, const bf16* __restrict__ vbuf, float* __restrict__ gs)
{
    int blk = blockIdx.x;          // b*392 + h*49 + r
    int r = blk % 49; int h = (blk / 49) & 7; int b = blk / 392;
    __shared__ float sc[HWSZ];
    __shared__ float red[256];
    __shared__ float wred[4][16];
    int tid = threadIdx.x;
    const bf16* kbase = kbuf + ((size_t)(b * 8 + h) * HWSZ) * 16;
    const bf16* vbase = vbuf + ((size_t)(b * 8 + h) * HWSZ) * 16;
    float q[16];
    #pragma unroll
    for (int d = 0; d < 16; d++)
        q[d] = qbuf[((size_t)b * 49 + r) * 128 + h * 16 + d] * 0.25f;
    float m = -1e30f;
    for (int n = tid; n < HWSZ; n += 256) {
        bf16x8 k0 = *reinterpret_cast<const bf16x8*>(kbase + (size_t)n * 16);
        bf16x8 k1 = *reinterpret_cast<const bf16x8*>(kbase + (size_t)n * 16 + 8);
        float s = 0.f;
        #pragma unroll
        for (int d = 0; d < 8; d++) s += q[d] * bu2f((unsigned short)k0[d]);
        #pragma unroll
        for (int d = 0; d < 8; d++) s += q[d + 8] * bu2f((unsigned short)k1[d]);
        sc[n] = s; m = fmaxf(m, s);
    }
    red[tid] = m; __syncthreads();
    for (int st = 128; st; st >>= 1) { if (tid < st) red[tid] = fmaxf(red[tid], red[tid + st]); __syncthreads(); }
    m = red[0]; __syncthreads();
    float ssum = 0.f;
    for (int n = tid; n < HWSZ; n += 256) { float e = expf(sc[n] - m); sc[n] = e; ssum += e; }
    red[tid] = ssum; __syncthreads();
    for (int st = 128; st; st >>= 1) { if (tid < st) red[tid] += red[tid + st]; __syncthreads(); }
    float inv = 1.f / red[0];
    float acc[16] = {};
    for (int n = tid; n < HWSZ; n += 256) {
        float a = sc[n] * inv;
        bf16x8 v0 = *reinterpret_cast<const bf16x8*>(vbase + (size_t)n * 16);
        bf16x8 v1 = *reinterpret_cast<const bf16x8*>(vbase + (size_t)n * 16 + 8);
        #pragma unroll
        for (int d = 0; d < 8; d++) acc[d] += a * bu2f((unsigned short)v0[d]);
        #pragma unroll
        for (int d = 0; d < 8; d++) acc[d + 8] += a * bu2f((unsigned short)v1[d]);
    }
    #pragma unroll
    for (int d = 0; d < 16; d++)
        for (int off = 32; off; off >>= 1) acc[d] += __shfl_xor(acc[d], off, 64);
    int wave = tid >> 6, lane = tid & 63;
    if (lane == 0)
        #pragma unroll
        for (int d = 0; d < 16; d++) wred[wave][d] = acc[d];
    __syncthreads();
    if (tid < 16)
        gs[(size_t)blk * 16 + tid] = wred[0][tid] + wred[1][tid] + wred[2][tid] + wred[3][tid];
}

// ---------------- bilinear 7->56 upsample into cat[:, 384:512] ----------------
__global__ void upsample_kernel(const float* __restrict__ gs, bf16* __restrict__ cat)
{
    int idx = blockIdx.x * blockDim.x + threadIdx.x;  // over N*128
    if (idx >= N_TOK * 128) return;
    int c = idx & 127;
    int pos = idx >> 7;
    int h = c >> 4, d = c & 15;
    int x = pos % 56;
    int y = (pos / 56) % 56;
    int b = pos / HWSZ;
    float sy = (y + 0.5f) * 0.125f - 0.5f;
    float sx = (x + 0.5f) * 0.125f - 0.5f;
    int y0f = (int)floorf(sy); float wy = sy - (float)y0f;
    int x0f = (int)floorf(sx); float wx = sx - (float)x0f;
    int y0 = max(0, min(6, y0f)), y1 = max(0, min(6, y0f + 1));
    int x0 = max(0, min(6, x0f)), x1 = max(0, min(6, x0f + 1));
    const float* g0 = gs + ((size_t)(b * 8 + h) * 49) * 16 + d;
    float v00 = g0[(y0 * 7 + x0) * 16], v01 = g0[(y0 * 7 + x1) * 16];
    float v10 = g0[(y1 * 7 + x0) * 16], v11 = g0[(y1 * 7 + x1) * 16];
    float v0 = v00 + (v01 - v00) * wx;
    float v1 = v10 + (v11 - v10) * wx;
    float v = v0 + (v1 - v0) * wy;
    cat[(size_t)pos * 512 + 384 + c] = __float2bfloat16(v);
}

extern "C" void kernel_launch(void* const* d_in, const int* in_sizes, int n_in,
                              void* d_out, int out_size, void* d_ws, size_t ws_size,
                              hipStream_t stream)
{
    const float* x      = (const float*)d_in[0];
    const float* x_e    = (const float*)d_in[1];
    const float* norm_w = (const float*)d_in[2];
    const float* norm_b = (const float*)d_in[3];
    const float* norme_w= (const float*)d_in[4];
    const float* norme_b= (const float*)d_in[5];
    const float* rr1_w  = (const float*)d_in[6];
    const float* rr1_b  = (const float*)d_in[7];
    const float* rr2_w  = (const float*)d_in[8];
    const float* rr2_b  = (const float*)d_in[9];
    const float* rr3_w  = (const float*)d_in[10];
    const float* rr3_b  = (const float*)d_in[11];
    const float* conv_w = (const float*)d_in[12];
    const float* conv_b = (const float*)d_in[13];
    const float* l1_w   = (const float*)d_in[14];
    const float* l1_b   = (const float*)d_in[15];
    const float* l2_w   = (const float*)d_in[16];
    const float* l2_b   = (const float*)d_in[17];
    const float* c1_w   = (const float*)d_in[18];
    const float* c1_b   = (const float*)d_in[19];
    const float* c2_w   = (const float*)d_in[20];
    const float* c2_b   = (const float*)d_in[21];
    const float* fc1_w  = (const float*)d_in[22];
    const float* fc2_w  = (const float*)d_in[23];
    const float* l3_w   = (const float*)d_in[24];
    const float* l3_b   = (const float*)d_in[25];
    const float* kv_w   = (const float*)d_in[26];
    const float* kv_b   = (const float*)d_in[27];
    const float* q_w    = (const float*)d_in[28];
    const float* q_b    = (const float*)d_in[29];
    const float* proj_w = (const float*)d_in[30];
    const float* proj_b = (const float*)d_in[31];
    const float* proje_w= (const float*)d_in[32];
    const float* proje_b= (const float*)d_in[33];

    // ---- workspace: fp32 smalls, bf16 transposed weights, bf16 slabs ----
    float* part   = (float*)d_ws;                 // 16*64*513
    float* attnc  = part   + (size_t)525312;      // 16*256
    float* gs     = attnc  + 4096;                // 16*8*49*16
    float* rxpool = gs     + 100352;              // 784*384
    float* qbuf   = rxpool + 301056;              // 784*128
    bf16* wt      = (bf16*)(qbuf + 100352);
    bf16* rr1_t  = wt;              // 256x256
    bf16* rr2_t  = rr1_t + 65536;
    bf16* rr3_t  = rr2_t + 65536;
    bf16* kv_t   = rr3_t + 65536;
    bf16* l1_t   = kv_t  + 65536;   // 128x256
    bf16* l2_t   = l1_t  + 32768;   // 128x128
    bf16* l3_t   = l2_t  + 16384;   // 128x256
    bf16* proj_t = l3_t  + 32768;   // 256x512
    bf16* proje_t= proj_t + 131072; // 128x512
    bf16* xn     = proje_t + 65536;
    bf16* xen    = xn   + (size_t)N_TOK * 256;
    bf16* bufC   = xen  + (size_t)N_TOK * 128;   // rr1 / codin / K|V head-major
    bf16* bufD   = bufC + (size_t)N_TOK * 256;   // rr2pre / rgb|t
    bf16* bufE   = bufD + (size_t)N_TOK * 256;   // conv out / co_di
    bf16* cat    = bufE + (size_t)N_TOK * 256;   // [N,512]
    size_t need = (size_t)((char*)(cat + (size_t)N_TOK * 512) - (char*)d_ws);
    if (ws_size < need) return;

    bf16* kbuf = bufC;                       // [B][8][HWSZ][16]
    bf16* vbuf = bufC + (size_t)N_TOK * 128;

    float* xout  = (float*)d_out;
    float* xeout = xout + (size_t)N_TOK * 256;

    const int nthr = 256;
    auto mgrid = [](int M, int N) { return dim3((M / 128) * (N / 128)); };

    // 0. weight prep (one launch)
    {
        WtrPack p;
        const float* srcs[9] = {rr1_w, rr2_w, rr3_w, kv_w, l1_w, l2_w, l3_w, proj_w, proje_w};
        bf16* dsts[9] = {rr1_t, rr2_t, rr3_t, kv_t, l1_t, l2_t, l3_t, proj_t, proje_t};
        int Ks[9] = {256, 256, 256, 256, 256, 128, 256, 512, 512};
        int Ns[9] = {256, 256, 256, 256, 128, 128, 128, 256, 128};
        int off = 0;
        for (int s = 0; s < 9; s++) {
            p.d[s] = {srcs[s], dsts[s], Ks[s], Ns[s], off};
            off += Ks[s] * Ns[s];
        }
        p.total = off;
        wtr_all<<<dim3((off + 255) / 256), dim3(256), 0, stream>>>(p);
    }

    // 1. LayerNorms
    ln_kernel<<<dim3(N_TOK / 4), dim3(nthr), 0, stream>>>(x, norm_w, norm_b, xn, N_TOK, 256);
    ln_kernel<<<dim3(N_TOK / 4), dim3(nthr), 0, stream>>>(x_e, norme_w, norme_b, xen, N_TOK, 128);

    // 2. local_rr -> cat[:, 0:256]
    gemm_mfma<0, bf16><<<mgrid(N_TOK, 256), dim3(nthr), 0, stream>>>(
        xn, 256, rr1_t, rr1_b, bufC, 256, N_TOK, 256, 256, nullptr, 0, nullptr, nullptr, nullptr);
    gemm_mfma<0, bf16><<<mgrid(N_TOK, 256), dim3(nthr), 0, stream>>>(
        xn, 256, rr2_t, rr2_b, bufD, 256, N_TOK, 256, 256, nullptr, 0, nullptr, nullptr, nullptr);
    dwconv_tile<<<dim3(BATCH * 56), dim3(nthr), 0, stream>>>(
        bufD, bufE, conv_w, conv_b, conv_w, conv_b, 256);
    gemm_mfma<GF_MUL, bf16><<<mgrid(N_TOK, 256), dim3(nthr), 0, stream>>>(
        bufE, 256, rr3_t, rr3_b, cat, 512, N_TOK, 256, 256, bufC, 256, nullptr, nullptr, nullptr);

    // 3. LocalAttentionRGBT -> cat[:, 256:384]
    gemm_mfma<0, bf16><<<mgrid(N_TOK, 128), dim3(nthr), 0, stream>>>(
        xn, 256, l1_t, l1_b, bufD, 128, N_TOK, 256, 128, nullptr, 0, nullptr, nullptr, nullptr);
    gemm_mfma<0, bf16><<<mgrid(N_TOK, 128), dim3(nthr), 0, stream>>>(
        xen, 128, l2_t, l2_b, bufD + (size_t)N_TOK * 128, 128, N_TOK, 128, 128, nullptr, 0, nullptr, nullptr, nullptr);
    rgbt_k<<<dim3((N_TOK * 128) / nthr), dim3(nthr), 0, stream>>>(
        bufD, bufD + (size_t)N_TOK * 128, bufC, N_TOK * 128);
    dwconv_tile<<<dim3(BATCH * 56), dim3(nthr), 0, stream>>>(
        bufC, bufE, c1_w, c1_b, c2_w, c2_b, 128);
    cosred_k<<<dim3(BATCH * 16), dim3(nthr), 0, stream>>>(bufE, part);
    mlp_kernel<<<dim3(BATCH), dim3(nthr), 0, stream>>>(part, fc1_w, fc2_w, attnc);
    gemm_mfma<GF_ASCALE, bf16><<<mgrid(N_TOK, 128), dim3(nthr), 0, stream>>>(
        bufE, 256, l3_t, l3_b, cat + 256, 512, N_TOK, 256, 128, nullptr, 0, attnc, nullptr, nullptr);

    // 4. global pooled attention -> cat[:, 384:512]
    gemm_mfma<GF_KVSPLIT, bf16><<<mgrid(N_TOK, 256), dim3(nthr), 0, stream>>>(
        xn, 256, kv_t, kv_b, (bf16*)nullptr, 0, N_TOK, 256, 256, nullptr, 0, nullptr, kbuf, vbuf);
    pool_kernel<<<dim3(BATCH * 49), dim3(384), 0, stream>>>(xn, xen, rxpool);
    gemm_k<<<dim3(((784 + 63) / 64) * 2), dim3(nthr), 0, stream>>>(
        rxpool, 384, q_w, q_b, qbuf, 128, 784, 384, 128);
    attn_kernel<<<dim3(BATCH * 8 * 49), dim3(nthr), 0, stream>>>(qbuf, kbuf, vbuf, gs);
    upsample_kernel<<<dim3((N_TOK * 128) / nthr), dim3(nthr), 0, stream>>>(gs, cat);

    // 5. output projections (fp32 out)
    gemm_mfma<0, float><<<mgrid(N_TOK, 256), dim3(nthr), 0, stream>>>(
        cat, 512, proj_t, proj_b, xout, 256, N_TOK, 512, 256, nullptr, 0, nullptr, nullptr, nullptr);
    gemm_mfma<0, float><<<mgrid(N_TOK, 128), dim3(nthr), 0, stream>>>(
        cat, 512, proje_t, proje_b, xeout, 128, N_TOK, 512, 128, nullptr, 0, nullptr, nullptr, nullptr);
}

// Round 2
// 555.444 us; speedup vs baseline: 1.3055x; 1.0676x over previous
//
#include <hip/hip_runtime.h>
#include <hip/hip_bf16.h>
#include <cstdint>
#include <cstddef>

#define N_TOK 50176      // B*H*W
#define HWSZ  3136       // 56*56
#define BATCH 16

#define GF_MUL     1
#define GF_ASCALE  2
#define GF_KVSPLIT 4

typedef __hip_bfloat16 bf16;
typedef __attribute__((ext_vector_type(8))) short bf16x8;
typedef __attribute__((ext_vector_type(4))) float f32x4;
typedef __attribute__((ext_vector_type(4))) unsigned short u16x4;

__device__ __forceinline__ void  stf(float* p, size_t i, float v) { p[i] = v; }
__device__ __forceinline__ void  stf(bf16* p, size_t i, float v) { p[i] = __float2bfloat16(v); }
__device__ __forceinline__ float bu2f(unsigned short u) {
    unsigned int x = ((unsigned int)u) << 16; float f; __builtin_memcpy(&f, &x, 4); return f;
}
__device__ __forceinline__ unsigned short f2bu(float f) {
    bf16 t = __float2bfloat16(f); unsigned short u; __builtin_memcpy(&u, &t, 2); return u;
}

// ---------------- batched weight prep: W[K][N] fp32 -> WT[N][K] bf16 (9 mats, 1 launch) ----------------
struct WtrDesc { const float* src; bf16* dst; int K; int N; int off; };
struct WtrPack { WtrDesc d[9]; int total; };
__global__ __launch_bounds__(256) void wtr_all(WtrPack p)
{
    int idx = blockIdx.x * 256 + threadIdx.x;
    if (idx >= p.total) return;
    #pragma unroll
    for (int s = 0; s < 9; s++) {
        int lo = p.d[s].off, hi = lo + p.d[s].K * p.d[s].N;
        if (idx >= lo && idx < hi) {
            int j = idx - lo;
            int k = j / p.d[s].N, n = j % p.d[s].N;
            p.d[s].dst[(size_t)n * p.d[s].K + k] = __float2bfloat16(p.d[s].src[j]);
        }
    }
}

// ---------------- LayerNorm: one wave per row (fp32 in -> bf16 out) ----------------
__global__ __launch_bounds__(256) void ln_kernel(const float* __restrict__ in,
    const float* __restrict__ w, const float* __restrict__ b,
    bf16* __restrict__ out, int rows, int Cdim)
{
    int wave = threadIdx.x >> 6, lane = threadIdx.x & 63;
    int row = blockIdx.x * 4 + wave;
    if (row >= rows) return;
    const float* p = in + (size_t)row * Cdim;
    int nj = Cdim >> 6;
    float v[4];
    float s = 0.f;
    for (int j = 0; j < nj; j++) { v[j] = p[lane + 64 * j]; s += v[j]; }
    for (int off = 32; off; off >>= 1) s += __shfl_xor(s, off, 64);
    float mean = s / (float)Cdim;
    float vs = 0.f;
    for (int j = 0; j < nj; j++) { float d = v[j] - mean; vs += d * d; }
    for (int off = 32; off; off >>= 1) vs += __shfl_xor(vs, off, 64);
    float rstd = 1.f / sqrtf(vs / (float)Cdim + 1e-6f);
    bf16* q = out + (size_t)row * Cdim;
    for (int j = 0; j < nj; j++) {
        int c = lane + 64 * j;
        q[c] = __float2bfloat16((v[j] - mean) * rstd * w[c] + b[c]);
    }
}

// ---------------- MFMA GEMM: C = A[M,K](bf16) @ WT[N,K]^T(bf16) + bias ----------------
// 128x128 tile, BK=32, 256 threads (4 waves 2x2), 16x16x32 MFMA, fp32 accum.
#define LDT 56   // padded LDS K-stride (112B: 16B-aligned, 2-way banks)
template<int FLAGS, typename OT>
__global__ __launch_bounds__(256) void gemm_mfma(
    const bf16* __restrict__ A, int lda,
    const bf16* __restrict__ WT,           // [N][K]
    const float* __restrict__ bias,
    OT* __restrict__ C, int ldc,
    int M, int K, int N,
    const bf16* __restrict__ mul, int mulld,
    const float* __restrict__ ascale,      // [BATCH][K]
    bf16* __restrict__ kout, bf16* __restrict__ vout)
{
    __shared__ bf16 As[128][LDT];
    __shared__ bf16 Bs[128][LDT];
    int ntile = N >> 7;
    int m0 = (blockIdx.x / ntile) * 128;
    int n0 = (blockIdx.x % ntile) * 128;
    int tid = threadIdx.x;
    int lane = tid & 63, wid = tid >> 6;
    int wr = (wid >> 1) * 64, wc = (wid & 1) * 64;
    int lrow = lane & 15, lko = (lane >> 4) * 8;

    f32x4 acc[4][4];
    #pragma unroll
    for (int i = 0; i < 4; i++)
        #pragma unroll
        for (int j = 0; j < 4; j++)
            acc[i][j] = (f32x4){0.f, 0.f, 0.f, 0.f};

    for (int k0 = 0; k0 < K; k0 += 32) {
        #pragma unroll
        for (int i = 0; i < 2; i++) {
            int idx = tid + i * 256;
            int r = idx >> 2, ko = (idx & 3) * 8;
            bf16x8 v = *reinterpret_cast<const bf16x8*>(A + (size_t)(m0 + r) * lda + k0 + ko);
            if (FLAGS & GF_ASCALE) {
                int bidx = (m0 + r) / HWSZ;
                const float* as = ascale + (size_t)bidx * K + k0 + ko;
                #pragma unroll
                for (int e = 0; e < 8; e++)
                    v[e] = (short)f2bu(bu2f((unsigned short)v[e]) * as[e]);
            }
            *reinterpret_cast<bf16x8*>(&As[r][ko]) = v;
            bf16x8 wv = *reinterpret_cast<const bf16x8*>(WT + (size_t)(n0 + r) * K + k0 + ko);
            *reinterpret_cast<bf16x8*>(&Bs[r][ko]) = wv;
        }
        __syncthreads();
        bf16x8 af[4], br[4];
        #pragma unroll
        for (int i = 0; i < 4; i++)
            af[i] = *reinterpret_cast<const bf16x8*>(&As[wr + i * 16 + lrow][lko]);
        #pragma unroll
        for (int j = 0; j < 4; j++)
            br[j] = *reinterpret_cast<const bf16x8*>(&Bs[wc + j * 16 + lrow][lko]);
        #pragma unroll
        for (int i = 0; i < 4; i++)
            #pragma unroll
            for (int j = 0; j < 4; j++)
                acc[i][j] = __builtin_amdgcn_mfma_f32_16x16x32_bf16(af[i], br[j], acc[i][j], 0, 0, 0);
        __syncthreads();
    }

    int orow = (lane >> 4) * 4;
    int ocol = lane & 15;
    #pragma unroll
    for (int i = 0; i < 4; i++) {
        #pragma unroll
        for (int j = 0; j < 4; j++) {
            #pragma unroll
            for (int p = 0; p < 4; p++) {
                int gm = m0 + wr + i * 16 + orow + p;
                int gn = n0 + wc + j * 16 + ocol;
                float v = acc[i][j][p] + bias[gn];
                if (FLAGS & GF_KVSPLIT) {
                    int bb = gm / HWSZ, n = gm % HWSZ;
                    if (gn < 128)
                        kout[(((size_t)bb * 8 + (gn >> 4)) * HWSZ + n) * 16 + (gn & 15)] = __float2bfloat16(v);
                    else
                        vout[(((size_t)bb * 8 + ((gn - 128) >> 4)) * HWSZ + n) * 16 + ((gn - 128) & 15)] = __float2bfloat16(v);
                } else {
                    if (FLAGS & GF_MUL) v *= __bfloat162float(mul[(size_t)gm * mulld + gn]);
                    stf(C, (size_t)gm * ldc + gn, v);
                }
            }
        }
    }
}

// ---------------- fp32 vector GEMM (small q projection only) ----------------
__global__ __launch_bounds__(256) void gemm_k(
    const float* __restrict__ A, int lda,
    const float* __restrict__ Wt, const float* __restrict__ bias,
    float* __restrict__ Cc, int ldc, int M, int K, int Nc)
{
    __shared__ float As[16][68];
    __shared__ float Ws[16][64];
    int ntile = Nc >> 6;
    int tile_n = blockIdx.x % ntile;
    int tile_m = blockIdx.x / ntile;
    int m0 = tile_m * 64, n0 = tile_n * 64;
    int tid = threadIdx.x;
    int tx = tid & 15, ty = tid >> 4;
    float acc[4][4] = {};
    for (int k0 = 0; k0 < K; k0 += 16) {
        int ks = tid & 15, ms = tid >> 4;
        #pragma unroll
        for (int i = 0; i < 4; i++) {
            int gm = m0 + ms + i * 16;
            As[ks][ms + i * 16] = (gm < M) ? A[(size_t)gm * lda + k0 + ks] : 0.f;
        }
        #pragma unroll
        for (int j = 0; j < 4; j++) {
            int k = (tid >> 6) * 4 + j;
            Ws[k][tid & 63] = Wt[(size_t)(k0 + k) * Nc + n0 + (tid & 63)];
        }
        __syncthreads();
        #pragma unroll
        for (int k = 0; k < 16; k++) {
            float a[4], w[4];
            #pragma unroll
            for (int i = 0; i < 4; i++) a[i] = As[k][ty * 4 + i];
            #pragma unroll
            for (int j = 0; j < 4; j++) w[j] = Ws[k][tx * 4 + j];
            #pragma unroll
            for (int i = 0; i < 4; i++)
                #pragma unroll
                for (int j = 0; j < 4; j++)
                    acc[i][j] += a[i] * w[j];
        }
        __syncthreads();
    }
    #pragma unroll
    for (int i = 0; i < 4; i++) {
        int gm = m0 + ty * 4 + i;
        if (gm >= M) continue;
        #pragma unroll
        for (int j = 0; j < 4; j++) {
            int gn = n0 + tx * 4 + j;
            Cc[(size_t)gm * ldc + gn] = acc[i][j] + bias[gn];
        }
    }
}

// ---------------- LDS-tiled depthwise 7x7 conv, x-register-reuse version ----------------
// Block: 448 threads (7 waves); tile = 8 rows x 28 cols x 64 ch.
// LDS: zero-padded (8+6) x (28+6) x 64 input tile = 60.9 KB -> 2 blocks/CU (14 waves).
// Thread: chg = 8-ch group, owns 4 CONSECUTIVE x positions in one row.
// Per ky: load 10 overlapping b128 (x-3..x+6) from LDS once, feed all 7 kx taps
// x 4 outputs from registers (70 ds_reads/thread vs 196 without reuse).
#define DW2_TX 28
#define DW2_TY 8
#define DW2_LC 34   // DW2_TX + 6
#define DW2_LR 14   // DW2_TY + 6
__global__ __launch_bounds__(448) void dwconv_tile(const bf16* __restrict__ in,
    bf16* __restrict__ out,
    const float* __restrict__ w0, const float* __restrict__ b0,
    const float* __restrict__ w1, const float* __restrict__ b1, int split)
{
    __shared__ bf16 tile[DW2_LR * DW2_LC * 64];
    int blk = blockIdx.x;
    int b = blk / 56;
    int r = blk % 56;
    int yt = r % 7;            // 7 row tiles
    int xt = (r / 7) & 1;      // 2 col tiles
    int cc = r / 14;           // 4 channel chunks of 64
    int ch0 = cc * 64;
    int x0g = xt * DW2_TX, y0g = yt * DW2_TY;
    int tid = threadIdx.x;

    // ---- stage zero-padded tile into LDS ----
    const bf16* base = in + (size_t)b * HWSZ * 256 + ch0;
    for (int idx = tid; idx < DW2_LR * DW2_LC * 8; idx += 448) {
        int c8 = idx & 7;
        int pos = idx >> 3;
        int col = pos % DW2_LC, row = pos / DW2_LC;
        int gy = y0g + row - 3, gx = x0g + col - 3;
        bf16x8 v = {0, 0, 0, 0, 0, 0, 0, 0};
        if (gy >= 0 && gy < 56 && gx >= 0 && gx < 56)
            v = *reinterpret_cast<const bf16x8*>(base + ((size_t)gy * 56 + gx) * 256 + c8 * 8);
        *reinterpret_cast<bf16x8*>(&tile[(size_t)idx * 8]) = v;
    }
    __syncthreads();

    // ---- thread mapping: row (0..7), xg (0..6, 4 cols each), chg (0..7, 8 ch each) ----
    int row = tid / 56;
    int rem = tid % 56;
    int xg = rem >> 3;
    int chg = rem & 7;

    const float* wp; const float* bp; int ws, cwt;
    if (ch0 < split) { wp = w0; bp = b0; ws = split;       cwt = ch0; }
    else             { wp = w1; bp = b1; ws = 256 - split; cwt = ch0 - split; }
    cwt += chg * 8;

    float acc[4][8];
    #pragma unroll
    for (int o = 0; o < 4; o++)
        #pragma unroll
        for (int e = 0; e < 8; e++) acc[o][e] = 0.f;

    const float* wbase = wp + cwt;
    #pragma unroll
    for (int ky = 0; ky < 7; ky++) {
        bf16x8 rr[10];
        int rb = ((row + ky) * DW2_LC + xg * 4) * 64 + chg * 8;
        #pragma unroll
        for (int j = 0; j < 10; j++)
            rr[j] = *reinterpret_cast<const bf16x8*>(&tile[rb + j * 64]);
        const float* wrow = wbase + ky * 7 * ws;
        #pragma unroll
        for (int kx = 0; kx < 7; kx++) {
            float4 wa = *reinterpret_cast<const float4*>(wrow + kx * ws);
            float4 wb = *reinterpret_cast<const float4*>(wrow + kx * ws + 4);
            #pragma unroll
            for (int o = 0; o < 4; o++) {
                bf16x8 v = rr[o + kx];
                acc[o][0] += bu2f((unsigned short)v[0]) * wa.x;
                acc[o][1] += bu2f((unsigned short)v[1]) * wa.y;
                acc[o][2] += bu2f((unsigned short)v[2]) * wa.z;
                acc[o][3] += bu2f((unsigned short)v[3]) * wa.w;
                acc[o][4] += bu2f((unsigned short)v[4]) * wb.x;
                acc[o][5] += bu2f((unsigned short)v[5]) * wb.y;
                acc[o][6] += bu2f((unsigned short)v[6]) * wb.z;
                acc[o][7] += bu2f((unsigned short)v[7]) * wb.w;
            }
        }
    }

    // ---- bias + store ----
    float4 ba = *reinterpret_cast<const float4*>(bp + cwt);
    float4 bb = *reinterpret_cast<const float4*>(bp + cwt + 4);
    bf16* obase = out + (size_t)b * HWSZ * 256 + ch0 + chg * 8;
    int gy = y0g + row;
    #pragma unroll
    for (int o = 0; o < 4; o++) {
        int gx = x0g + xg * 4 + o;
        bf16x8 ov;
        ov[0] = (short)f2bu(acc[o][0] + ba.x);
        ov[1] = (short)f2bu(acc[o][1] + ba.y);
        ov[2] = (short)f2bu(acc[o][2] + ba.z);
        ov[3] = (short)f2bu(acc[o][3] + ba.w);
        ov[4] = (short)f2bu(acc[o][4] + bb.x);
        ov[5] = (short)f2bu(acc[o][5] + bb.y);
        ov[6] = (short)f2bu(acc[o][6] + bb.z);
        ov[7] = (short)f2bu(acc[o][7] + bb.w);
        *reinterpret_cast<bf16x8*>(obase + ((size_t)gy * 56 + gx) * 256) = ov;
    }
}

// ---------------- rgb/t elementwise -> codin[N,256] ----------------
__global__ void rgbt_k(const bf16* __restrict__ rgb, const bf16* __restrict__ t,
                       bf16* __restrict__ codin, int total /* N*128 */)
{
    int i = blockIdx.x * blockDim.x + threadIdx.x;
    if (i >= total) return;
    int n = i >> 7, c = i & 127;
    float a = __bfloat162float(rgb[i]), bb = __bfloat162float(t[i]);
    codin[(size_t)n * 256 + c] = __float2bfloat16(a * bb);
    codin[(size_t)n * 256 + 128 + c] = __float2bfloat16(fabsf(a - bb));
}

// ---------------- cosine-gate partial reductions ----------------
__global__ __launch_bounds__(256) void cosred_k(const bf16* __restrict__ codi,
    float* __restrict__ part)   // [B][64][513]
{
    int b = blockIdx.x >> 4;
    int bi = blockIdx.x & 15;
    int wave = threadIdx.x >> 6, lane = threadIdx.x & 63;
    int slot = bi * 4 + wave;
    float dloc[4] = {0,0,0,0}, n2loc[4] = {0,0,0,0};
    float n1loc = 0.f;
    for (int i = 0; i < 49; i++) {
        int p = slot * 49 + i;
        const bf16* row = codi + ((size_t)b * HWSZ + p) * 256;
        float v[4]; float sum = 0.f;
        #pragma unroll
        for (int j = 0; j < 4; j++) { v[j] = __bfloat162float(row[lane + 64 * j]); sum += v[j]; }
        for (int off = 32; off; off >>= 1) sum += __shfl_xor(sum, off, 64);
        float amap = sum * (1.f / 256.f);
        #pragma unroll
        for (int j = 0; j < 4; j++) { dloc[j] += amap * v[j]; n2loc[j] += v[j] * v[j]; }
        n1loc += amap * amap;
    }
    float* dst = part + ((size_t)b * 64 + slot) * 513;
    #pragma unroll
    for (int j = 0; j < 4; j++) {
        dst[lane + 64 * j] = dloc[j];
        dst[256 + lane + 64 * j] = n2loc[j];
    }
    if (lane == 0) dst[512] = n1loc;
}

// ---------------- cos_sim + MLP + sigmoid -> attn_c[B,256] fp32 ----------------
__global__ __launch_bounds__(256) void mlp_kernel(const float* __restrict__ part,
    const float* __restrict__ fc1w, const float* __restrict__ fc2w,
    float* __restrict__ attnc)
{
    int b = blockIdx.x;
    int tid = threadIdx.x;
    __shared__ float cosb[256];
    __shared__ float hbuf[32];
    const float* pb = part + (size_t)b * 64 * 513;
    float dot = 0.f, n2 = 0.f, n1 = 0.f;
    for (int s = 0; s < 64; s++) {
        dot += pb[s * 513 + tid];
        n2  += pb[s * 513 + 256 + tid];
        n1  += pb[s * 513 + 512];
    }
    float cs = dot / (sqrtf(n1) * sqrtf(n2) + 1e-6f);
    cosb[tid] = cs;
    __syncthreads();
    if (tid < 32) {
        float h = 0.f;
        for (int c = 0; c < 256; c++) h += cosb[c] * fc1w[c * 32 + tid];
        h = 0.5f * h * (1.f + erff(h * 0.70710678f));
        hbuf[tid] = h;
    }
    __syncthreads();
    float o = 0.f;
    for (int j = 0; j < 32; j++) o += hbuf[j] * fc2w[j * 256 + tid];
    attnc[b * 256 + tid] = 1.f / (1.f + expf(-o));
}

// ---------------- 8x8 mean-pool of concat(xn, xen) -> rx_pool[B,49,384] fp32 ----------------
__global__ __launch_bounds__(384) void pool_kernel(const bf16* __restrict__ xn,
    const bf16* __restrict__ xen, float* __restrict__ rxpool)
{
    int bij = blockIdx.x;
    int b = bij / 49; int ij = bij % 49; int i = ij / 7, j = ij % 7;
    int c = threadIdx.x;
    float s = 0.f;
    for (int dy = 0; dy < 8; dy++)
        for (int dx = 0; dx < 8; dx++) {
            size_t n = ((size_t)b * 56 + (i * 8 + dy)) * 56 + (j * 8 + dx);
            s += (c < 256) ? __bfloat162float(xn[n * 256 + c])
                           : __bfloat162float(xen[n * 128 + (c - 256)]);
        }
    rxpool[(size_t)bij * 384 + c] = s * (1.f / 64.f);
}

// ---------------- fused scores->softmax->A@V per (b,h,q), head-major K/V ----------------
__global__ __launch_bounds__(256) void attn_kernel(const float* __restrict__ qbuf,
    const bf16* __restrict__ kbuf, const bf16* __restrict__ vbuf, float* __restrict__ gs)
{
    int blk = blockIdx.x;          // b*392 + h*49 + r
    int r = blk % 49; int h = (blk / 49) & 7; int b = blk / 392;
    __shared__ float sc[HWSZ];
    __shared__ float red[256];
    __shared__ float wred[4][16];
    int tid = threadIdx.x;
    const bf16* kbase = kbuf + ((size_t)(b * 8 + h) * HWSZ) * 16;
    const bf16* vbase = vbuf + ((size_t)(b * 8 + h) * HWSZ) * 16;
    float q[16];
    #pragma unroll
    for (int d = 0; d < 16; d++)
        q[d] = qbuf[((size_t)b * 49 + r) * 128 + h * 16 + d] * 0.25f;
    float m = -1e30f;
    for (int n = tid; n < HWSZ; n += 256) {
        bf16x8 k0 = *reinterpret_cast<const bf16x8*>(kbase + (size_t)n * 16);
        bf16x8 k1 = *reinterpret_cast<const bf16x8*>(kbase + (size_t)n * 16 + 8);
        float s = 0.f;
        #pragma unroll
        for (int d = 0; d < 8; d++) s += q[d] * bu2f((unsigned short)k0[d]);
        #pragma unroll
        for (int d = 0; d < 8; d++) s += q[d + 8] * bu2f((unsigned short)k1[d]);
        sc[n] = s; m = fmaxf(m, s);
    }
    red[tid] = m; __syncthreads();
    for (int st = 128; st; st >>= 1) { if (tid < st) red[tid] = fmaxf(red[tid], red[tid + st]); __syncthreads(); }
    m = red[0]; __syncthreads();
    float ssum = 0.f;
    for (int n = tid; n < HWSZ; n += 256) { float e = expf(sc[n] - m); sc[n] = e; ssum += e; }
    red[tid] = ssum; __syncthreads();
    for (int st = 128; st; st >>= 1) { if (tid < st) red[tid] += red[tid + st]; __syncthreads(); }
    float inv = 1.f / red[0];
    float acc[16] = {};
    for (int n = tid; n < HWSZ; n += 256) {
        float a = sc[n] * inv;
        bf16x8 v0 = *reinterpret_cast<const bf16x8*>(vbase + (size_t)n * 16);
        bf16x8 v1 = *reinterpret_cast<const bf16x8*>(vbase + (size_t)n * 16 + 8);
        #pragma unroll
        for (int d = 0; d < 8; d++) acc[d] += a * bu2f((unsigned short)v0[d]);
        #pragma unroll
        for (int d = 0; d < 8; d++) acc[d + 8] += a * bu2f((unsigned short)v1[d]);
    }
    #pragma unroll
    for (int d = 0; d < 16; d++)
        for (int off = 32; off; off >>= 1) acc[d] += __shfl_xor(acc[d], off, 64);
    int wave = tid >> 6, lane = tid & 63;
    if (lane == 0)
        #pragma unroll
        for (int d = 0; d < 16; d++) wred[wave][d] = acc[d];
    __syncthreads();
    if (tid < 16)
        gs[(size_t)blk * 16 + tid] = wred[0][tid] + wred[1][tid] + wred[2][tid] + wred[3][tid];
}

// ---------------- bilinear 7->56 upsample into cat[:, 384:512] ----------------
__global__ void upsample_kernel(const float* __restrict__ gs, bf16* __restrict__ cat)
{
    int idx = blockIdx.x * blockDim.x + threadIdx.x;  // over N*128
    if (idx >= N_TOK * 128) return;
    int c = idx & 127;
    int pos = idx >> 7;
    int h = c >> 4, d = c & 15;
    int x = pos % 56;
    int y = (pos / 56) % 56;
    int b = pos / HWSZ;
    float sy = (y + 0.5f) * 0.125f - 0.5f;
    float sx = (x + 0.5f) * 0.125f - 0.5f;
    int y0f = (int)floorf(sy); float wy = sy - (float)y0f;
    int x0f = (int)floorf(sx); float wx = sx - (float)x0f;
    int y0 = max(0, min(6, y0f)), y1 = max(0, min(6, y0f + 1));
    int x0 = max(0, min(6, x0f)), x1 = max(0, min(6, x0f + 1));
    const float* g0 = gs + ((size_t)(b * 8 + h) * 49) * 16 + d;
    float v00 = g0[(y0 * 7 + x0) * 16], v01 = g0[(y0 * 7 + x1) * 16];
    float v10 = g0[(y1 * 7 + x0) * 16], v11 = g0[(y1 * 7 + x1) * 16];
    float v0 = v00 + (v01 - v00) * wx;
    float v1 = v10 + (v11 - v10) * wx;
    float v = v0 + (v1 - v0) * wy;
    cat[(size_t)pos * 512 + 384 + c] = __float2bfloat16(v);
}

extern "C" void kernel_launch(void* const* d_in, const int* in_sizes, int n_in,
                              void* d_out, int out_size, void* d_ws, size_t ws_size,
                              hipStream_t stream)
{
    const float* x      = (const float*)d_in[0];
    const float* x_e    = (const float*)d_in[1];
    const float* norm_w = (const float*)d_in[2];
    const float* norm_b = (const float*)d_in[3];
    const float* norme_w= (const float*)d_in[4];
    const float* norme_b= (const float*)d_in[5];
    const float* rr1_w  = (const float*)d_in[6];
    const float* rr1_b  = (const float*)d_in[7];
    const float* rr2_w  = (const float*)d_in[8];
    const float* rr2_b  = (const float*)d_in[9];
    const float* rr3_w  = (const float*)d_in[10];
    const float* rr3_b  = (const float*)d_in[11];
    const float* conv_w = (const float*)d_in[12];
    const float* conv_b = (const float*)d_in[13];
    const float* l1_w   = (const float*)d_in[14];
    const float* l1_b   = (const float*)d_in[15];
    const float* l2_w   = (const float*)d_in[16];
    const float* l2_b   = (const float*)d_in[17];
    const float* c1_w   = (const float*)d_in[18];
    const float* c1_b   = (const float*)d_in[19];
    const float* c2_w   = (const float*)d_in[20];
    const float* c2_b   = (const float*)d_in[21];
    const float* fc1_w  = (const float*)d_in[22];
    const float* fc2_w  = (const float*)d_in[23];
    const float* l3_w   = (const float*)d_in[24];
    const float* l3_b   = (const float*)d_in[25];
    const float* kv_w   = (const float*)d_in[26];
    const float* kv_b   = (const float*)d_in[27];
    const float* q_w    = (const float*)d_in[28];
    const float* q_b    = (const float*)d_in[29];
    const float* proj_w = (const float*)d_in[30];
    const float* proj_b = (const float*)d_in[31];
    const float* proje_w= (const float*)d_in[32];
    const float* proje_b= (const float*)d_in[33];

    // ---- workspace: fp32 smalls, bf16 transposed weights, bf16 slabs ----
    float* part   = (float*)d_ws;                 // 16*64*513
    float* attnc  = part   + (size_t)525312;      // 16*256
    float* gs     = attnc  + 4096;                // 16*8*49*16
    float* rxpool = gs     + 100352;              // 784*384
    float* qbuf   = rxpool + 301056;              // 784*128
    bf16* wt      = (bf16*)(qbuf + 100352);
    bf16* rr1_t  = wt;              // 256x256
    bf16* rr2_t  = rr1_t + 65536;
    bf16* rr3_t  = rr2_t + 65536;
    bf16* kv_t   = rr3_t + 65536;
    bf16* l1_t   = kv_t  + 65536;   // 128x256
    bf16* l2_t   = l1_t  + 32768;   // 128x128
    bf16* l3_t   = l2_t  + 16384;   // 128x256
    bf16* proj_t = l3_t  + 32768;   // 256x512
    bf16* proje_t= proj_t + 131072; // 128x512
    bf16* xn     = proje_t + 65536;
    bf16* xen    = xn   + (size_t)N_TOK * 256;
    bf16* bufC   = xen  + (size_t)N_TOK * 128;   // rr1 / codin / K|V head-major
    bf16* bufD   = bufC + (size_t)N_TOK * 256;   // rr2pre / rgb|t
    bf16* bufE   = bufD + (size_t)N_TOK * 256;   // conv out / co_di
    bf16* cat    = bufE + (size_t)N_TOK * 256;   // [N,512]
    size_t need = (size_t)((char*)(cat + (size_t)N_TOK * 512) - (char*)d_ws);
    if (ws_size < need) return;

    bf16* kbuf = bufC;                       // [B][8][HWSZ][16]
    bf16* vbuf = bufC + (size_t)N_TOK * 128;

    float* xout  = (float*)d_out;
    float* xeout = xout + (size_t)N_TOK * 256;

    const int nthr = 256;
    auto mgrid = [](int M, int N) { return dim3((M / 128) * (N / 128)); };

    // 0. weight prep (one launch)
    {
        WtrPack p;
        const float* srcs[9] = {rr1_w, rr2_w, rr3_w, kv_w, l1_w, l2_w, l3_w, proj_w, proje_w};
        bf16* dsts[9] = {rr1_t, rr2_t, rr3_t, kv_t, l1_t, l2_t, l3_t, proj_t, proje_t};
        int Ks[9] = {256, 256, 256, 256, 256, 128, 256, 512, 512};
        int Ns[9] = {256, 256, 256, 256, 128, 128, 128, 256, 128};
        int off = 0;
        for (int s = 0; s < 9; s++) {
            p.d[s] = {srcs[s], dsts[s], Ks[s], Ns[s], off};
            off += Ks[s] * Ns[s];
        }
        p.total = off;
        wtr_all<<<dim3((off + 255) / 256), dim3(256), 0, stream>>>(p);
    }

    // 1. LayerNorms
    ln_kernel<<<dim3(N_TOK / 4), dim3(nthr), 0, stream>>>(x, norm_w, norm_b, xn, N_TOK, 256);
    ln_kernel<<<dim3(N_TOK / 4), dim3(nthr), 0, stream>>>(x_e, norme_w, norme_b, xen, N_TOK, 128);

    // 2. local_rr -> cat[:, 0:256]
    gemm_mfma<0, bf16><<<mgrid(N_TOK, 256), dim3(nthr), 0, stream>>>(
        xn, 256, rr1_t, rr1_b, bufC, 256, N_TOK, 256, 256, nullptr, 0, nullptr, nullptr, nullptr);
    gemm_mfma<0, bf16><<<mgrid(N_TOK, 256), dim3(nthr), 0, stream>>>(
        xn, 256, rr2_t, rr2_b, bufD, 256, N_TOK, 256, 256, nullptr, 0, nullptr, nullptr, nullptr);
    dwconv_tile<<<dim3(BATCH * 56), dim3(448), 0, stream>>>(
        bufD, bufE, conv_w, conv_b, conv_w, conv_b, 256);
    gemm_mfma<GF_MUL, bf16><<<mgrid(N_TOK, 256), dim3(nthr), 0, stream>>>(
        bufE, 256, rr3_t, rr3_b, cat, 512, N_TOK, 256, 256, bufC, 256, nullptr, nullptr, nullptr);

    // 3. LocalAttentionRGBT -> cat[:, 256:384]
    gemm_mfma<0, bf16><<<mgrid(N_TOK, 128), dim3(nthr), 0, stream>>>(
        xn, 256, l1_t, l1_b, bufD, 128, N_TOK, 256, 128, nullptr, 0, nullptr, nullptr, nullptr);
    gemm_mfma<0, bf16><<<mgrid(N_TOK, 128), dim3(nthr), 0, stream>>>(
        xen, 128, l2_t, l2_b, bufD + (size_t)N_TOK * 128, 128, N_TOK, 128, 128, nullptr, 0, nullptr, nullptr, nullptr);
    rgbt_k<<<dim3((N_TOK * 128) / nthr), dim3(nthr), 0, stream>>>(
        bufD, bufD + (size_t)N_TOK * 128, bufC, N_TOK * 128);
    dwconv_tile<<<dim3(BATCH * 56), dim3(448), 0, stream>>>(
        bufC, bufE, c1_w, c1_b, c2_w, c2_b, 128);
    cosred_k<<<dim3(BATCH * 16), dim3(nthr), 0, stream>>>(bufE, part);
    mlp_kernel<<<dim3(BATCH), dim3(nthr), 0, stream>>>(part, fc1_w, fc2_w, attnc);
    gemm_mfma<GF_ASCALE, bf16><<<mgrid(N_TOK, 128), dim3(nthr), 0, stream>>>(
        bufE, 256, l3_t, l3_b, cat + 256, 512, N_TOK, 256, 128, nullptr, 0, attnc, nullptr, nullptr);

    // 4. global pooled attention -> cat[:, 384:512]
    gemm_mfma<GF_KVSPLIT, bf16><<<mgrid(N_TOK, 256), dim3(nthr), 0, stream>>>(
        xn, 256, kv_t, kv_b, (bf16*)nullptr, 0, N_TOK, 256, 256, nullptr, 0, nullptr, kbuf, vbuf);
    pool_kernel<<<dim3(BATCH * 49), dim3(384), 0, stream>>>(xn, xen, rxpool);
    gemm_k<<<dim3(((784 + 63) / 64) * 2), dim3(nthr), 0, stream>>>(
        rxpool, 384, q_w, q_b, qbuf, 128, 784, 384, 128);
    attn_kernel<<<dim3(BATCH * 8 * 49), dim3(nthr), 0, stream>>>(qbuf, kbuf, vbuf, gs);
    upsample_kernel<<<dim3((N_TOK * 128) / nthr), dim3(nthr), 0, stream>>>(gs, cat);

    // 5. output projections (fp32 out)
    gemm_mfma<0, float><<<mgrid(N_TOK, 256), dim3(nthr), 0, stream>>>(
        cat, 512, proj_t, proj_b, xout, 256, N_TOK, 512, 256, nullptr, 0, nullptr, nullptr, nullptr);
    gemm_mfma<0, float><<<mgrid(N_TOK, 128), dim3(nthr), 0, stream>>>(
        cat, 512, proje_t, proje_b, xeout, 128, N_TOK, 512, 128, nullptr, 0, nullptr, nullptr, nullptr);
}

// Round 3
// 531.088 us; speedup vs baseline: 1.3654x; 1.0459x over previous
//
#include <hip/hip_runtime.h>
#include <hip/hip_bf16.h>
#include <cstdint>
#include <cstddef>

#define N_TOK 50176      // B*H*W
#define HWSZ  3136       // 56*56
#define BATCH 16

#define GF_MUL     1
#define GF_ASCALE  2
#define GF_KVSPLIT 4

typedef __hip_bfloat16 bf16;
typedef __attribute__((ext_vector_type(8))) short bf16x8;
typedef __attribute__((ext_vector_type(4))) float f32x4;
typedef __attribute__((ext_vector_type(4))) unsigned short u16x4;

__device__ __forceinline__ void  stf(float* p, size_t i, float v) { p[i] = v; }
__device__ __forceinline__ void  stf(bf16* p, size_t i, float v) { p[i] = __float2bfloat16(v); }
__device__ __forceinline__ float bu2f(unsigned short u) {
    unsigned int x = ((unsigned int)u) << 16; float f; __builtin_memcpy(&f, &x, 4); return f;
}
__device__ __forceinline__ unsigned short f2bu(float f) {
    bf16 t = __float2bfloat16(f); unsigned short u; __builtin_memcpy(&u, &t, 2); return u;
}

// ---------------- batched weight prep: W[K][N] fp32 -> WT[N][K] bf16 (9 mats, 1 launch) ----------------
struct WtrDesc { const float* src; bf16* dst; int K; int N; int off; };
struct WtrPack { WtrDesc d[9]; int total; };
__global__ __launch_bounds__(256) void wtr_all(WtrPack p)
{
    int idx = blockIdx.x * 256 + threadIdx.x;
    if (idx >= p.total) return;
    #pragma unroll
    for (int s = 0; s < 9; s++) {
        int lo = p.d[s].off, hi = lo + p.d[s].K * p.d[s].N;
        if (idx >= lo && idx < hi) {
            int j = idx - lo;
            int k = j / p.d[s].N, n = j % p.d[s].N;
            p.d[s].dst[(size_t)n * p.d[s].K + k] = __float2bfloat16(p.d[s].src[j]);
        }
    }
}

// ---------------- LayerNorm: one wave per row (fp32 in -> bf16 out) ----------------
__global__ __launch_bounds__(256) void ln_kernel(const float* __restrict__ in,
    const float* __restrict__ w, const float* __restrict__ b,
    bf16* __restrict__ out, int rows, int Cdim)
{
    int wave = threadIdx.x >> 6, lane = threadIdx.x & 63;
    int row = blockIdx.x * 4 + wave;
    if (row >= rows) return;
    const float* p = in + (size_t)row * Cdim;
    int nj = Cdim >> 6;
    float v[4];
    float s = 0.f;
    for (int j = 0; j < nj; j++) { v[j] = p[lane + 64 * j]; s += v[j]; }
    for (int off = 32; off; off >>= 1) s += __shfl_xor(s, off, 64);
    float mean = s / (float)Cdim;
    float vs = 0.f;
    for (int j = 0; j < nj; j++) { float d = v[j] - mean; vs += d * d; }
    for (int off = 32; off; off >>= 1) vs += __shfl_xor(vs, off, 64);
    float rstd = 1.f / sqrtf(vs / (float)Cdim + 1e-6f);
    bf16* q = out + (size_t)row * Cdim;
    for (int j = 0; j < nj; j++) {
        int c = lane + 64 * j;
        q[c] = __float2bfloat16((v[j] - mean) * rstd * w[c] + b[c]);
    }
}

// ---------------- MFMA GEMM: C = A[M,K](bf16) @ WT[N,K]^T(bf16) + bias ----------------
// 128x128 tile, BK=32, 256 threads (4 waves 2x2), 16x16x32 MFMA, fp32 accum.
#define LDT 56   // padded LDS K-stride (112B: 16B-aligned, 2-way banks)
template<int FLAGS, typename OT>
__global__ __launch_bounds__(256) void gemm_mfma(
    const bf16* __restrict__ A, int lda,
    const bf16* __restrict__ WT,           // [N][K]
    const float* __restrict__ bias,
    OT* __restrict__ C, int ldc,
    int M, int K, int N,
    const bf16* __restrict__ mul, int mulld,
    const float* __restrict__ ascale,      // [BATCH][K]
    bf16* __restrict__ kout, bf16* __restrict__ vout)
{
    __shared__ bf16 As[128][LDT];
    __shared__ bf16 Bs[128][LDT];
    int ntile = N >> 7;
    int m0 = (blockIdx.x / ntile) * 128;
    int n0 = (blockIdx.x % ntile) * 128;
    int tid = threadIdx.x;
    int lane = tid & 63, wid = tid >> 6;
    int wr = (wid >> 1) * 64, wc = (wid & 1) * 64;
    int lrow = lane & 15, lko = (lane >> 4) * 8;

    f32x4 acc[4][4];
    #pragma unroll
    for (int i = 0; i < 4; i++)
        #pragma unroll
        for (int j = 0; j < 4; j++)
            acc[i][j] = (f32x4){0.f, 0.f, 0.f, 0.f};

    for (int k0 = 0; k0 < K; k0 += 32) {
        #pragma unroll
        for (int i = 0; i < 2; i++) {
            int idx = tid + i * 256;
            int r = idx >> 2, ko = (idx & 3) * 8;
            bf16x8 v = *reinterpret_cast<const bf16x8*>(A + (size_t)(m0 + r) * lda + k0 + ko);
            if (FLAGS & GF_ASCALE) {
                int bidx = (m0 + r) / HWSZ;
                const float* as = ascale + (size_t)bidx * K + k0 + ko;
                #pragma unroll
                for (int e = 0; e < 8; e++)
                    v[e] = (short)f2bu(bu2f((unsigned short)v[e]) * as[e]);
            }
            *reinterpret_cast<bf16x8*>(&As[r][ko]) = v;
            bf16x8 wv = *reinterpret_cast<const bf16x8*>(WT + (size_t)(n0 + r) * K + k0 + ko);
            *reinterpret_cast<bf16x8*>(&Bs[r][ko]) = wv;
        }
        __syncthreads();
        bf16x8 af[4], br[4];
        #pragma unroll
        for (int i = 0; i < 4; i++)
            af[i] = *reinterpret_cast<const bf16x8*>(&As[wr + i * 16 + lrow][lko]);
        #pragma unroll
        for (int j = 0; j < 4; j++)
            br[j] = *reinterpret_cast<const bf16x8*>(&Bs[wc + j * 16 + lrow][lko]);
        #pragma unroll
        for (int i = 0; i < 4; i++)
            #pragma unroll
            for (int j = 0; j < 4; j++)
                acc[i][j] = __builtin_amdgcn_mfma_f32_16x16x32_bf16(af[i], br[j], acc[i][j], 0, 0, 0);
        __syncthreads();
    }

    int orow = (lane >> 4) * 4;
    int ocol = lane & 15;
    #pragma unroll
    for (int i = 0; i < 4; i++) {
        #pragma unroll
        for (int j = 0; j < 4; j++) {
            #pragma unroll
            for (int p = 0; p < 4; p++) {
                int gm = m0 + wr + i * 16 + orow + p;
                int gn = n0 + wc + j * 16 + ocol;
                float v = acc[i][j][p] + bias[gn];
                if (FLAGS & GF_KVSPLIT) {
                    int bb = gm / HWSZ, n = gm % HWSZ;
                    if (gn < 128)
                        kout[(((size_t)bb * 8 + (gn >> 4)) * HWSZ + n) * 16 + (gn & 15)] = __float2bfloat16(v);
                    else {
                        int hh = (gn - 128) >> 4, dd = (gn - 128) & 15;
                        // V stored TRANSPOSED: [bh][d][pos]
                        vout[(((size_t)bb * 8 + hh) * 16 + dd) * HWSZ + n] = __float2bfloat16(v);
                    }
                } else {
                    if (FLAGS & GF_MUL) v *= __bfloat162float(mul[(size_t)gm * mulld + gn]);
                    stf(C, (size_t)gm * ldc + gn, v);
                }
            }
        }
    }
}

// ---------------- fp32 vector GEMM (small q projection only) ----------------
__global__ __launch_bounds__(256) void gemm_k(
    const float* __restrict__ A, int lda,
    const float* __restrict__ Wt, const float* __restrict__ bias,
    float* __restrict__ Cc, int ldc, int M, int K, int Nc)
{
    __shared__ float As[16][68];
    __shared__ float Ws[16][64];
    int ntile = Nc >> 6;
    int tile_n = blockIdx.x % ntile;
    int tile_m = blockIdx.x / ntile;
    int m0 = tile_m * 64, n0 = tile_n * 64;
    int tid = threadIdx.x;
    int tx = tid & 15, ty = tid >> 4;
    float acc[4][4] = {};
    for (int k0 = 0; k0 < K; k0 += 16) {
        int ks = tid & 15, ms = tid >> 4;
        #pragma unroll
        for (int i = 0; i < 4; i++) {
            int gm = m0 + ms + i * 16;
            As[ks][ms + i * 16] = (gm < M) ? A[(size_t)gm * lda + k0 + ks] : 0.f;
        }
        #pragma unroll
        for (int j = 0; j < 4; j++) {
            int k = (tid >> 6) * 4 + j;
            Ws[k][tid & 63] = Wt[(size_t)(k0 + k) * Nc + n0 + (tid & 63)];
        }
        __syncthreads();
        #pragma unroll
        for (int k = 0; k < 16; k++) {
            float a[4], w[4];
            #pragma unroll
            for (int i = 0; i < 4; i++) a[i] = As[k][ty * 4 + i];
            #pragma unroll
            for (int j = 0; j < 4; j++) w[j] = Ws[k][tx * 4 + j];
            #pragma unroll
            for (int i = 0; i < 4; i++)
                #pragma unroll
                for (int j = 0; j < 4; j++)
                    acc[i][j] += a[i] * w[j];
        }
        __syncthreads();
    }
    #pragma unroll
    for (int i = 0; i < 4; i++) {
        int gm = m0 + ty * 4 + i;
        if (gm >= M) continue;
        #pragma unroll
        for (int j = 0; j < 4; j++) {
            int gn = n0 + tx * 4 + j;
            Cc[(size_t)gm * ldc + gn] = acc[i][j] + bias[gn];
        }
    }
}

// ---------------- LDS-tiled depthwise 7x7 conv, x-register-reuse version ----------------
#define DW2_TX 28
#define DW2_TY 8
#define DW2_LC 34   // DW2_TX + 6
#define DW2_LR 14   // DW2_TY + 6
__global__ __launch_bounds__(448) void dwconv_tile(const bf16* __restrict__ in,
    bf16* __restrict__ out,
    const float* __restrict__ w0, const float* __restrict__ b0,
    const float* __restrict__ w1, const float* __restrict__ b1, int split)
{
    __shared__ bf16 tile[DW2_LR * DW2_LC * 64];
    int blk = blockIdx.x;
    int b = blk / 56;
    int r = blk % 56;
    int yt = r % 7;            // 7 row tiles
    int xt = (r / 7) & 1;      // 2 col tiles
    int cc = r / 14;           // 4 channel chunks of 64
    int ch0 = cc * 64;
    int x0g = xt * DW2_TX, y0g = yt * DW2_TY;
    int tid = threadIdx.x;

    // ---- stage zero-padded tile into LDS ----
    const bf16* base = in + (size_t)b * HWSZ * 256 + ch0;
    for (int idx = tid; idx < DW2_LR * DW2_LC * 8; idx += 448) {
        int c8 = idx & 7;
        int pos = idx >> 3;
        int col = pos % DW2_LC, row = pos / DW2_LC;
        int gy = y0g + row - 3, gx = x0g + col - 3;
        bf16x8 v = {0, 0, 0, 0, 0, 0, 0, 0};
        if (gy >= 0 && gy < 56 && gx >= 0 && gx < 56)
            v = *reinterpret_cast<const bf16x8*>(base + ((size_t)gy * 56 + gx) * 256 + c8 * 8);
        *reinterpret_cast<bf16x8*>(&tile[(size_t)idx * 8]) = v;
    }
    __syncthreads();

    int row = tid / 56;
    int rem = tid % 56;
    int xg = rem >> 3;
    int chg = rem & 7;

    const float* wp; const float* bp; int ws, cwt;
    if (ch0 < split) { wp = w0; bp = b0; ws = split;       cwt = ch0; }
    else             { wp = w1; bp = b1; ws = 256 - split; cwt = ch0 - split; }
    cwt += chg * 8;

    float acc[4][8];
    #pragma unroll
    for (int o = 0; o < 4; o++)
        #pragma unroll
        for (int e = 0; e < 8; e++) acc[o][e] = 0.f;

    const float* wbase = wp + cwt;
    #pragma unroll
    for (int ky = 0; ky < 7; ky++) {
        bf16x8 rr[10];
        int rb = ((row + ky) * DW2_LC + xg * 4) * 64 + chg * 8;
        #pragma unroll
        for (int j = 0; j < 10; j++)
            rr[j] = *reinterpret_cast<const bf16x8*>(&tile[rb + j * 64]);
        const float* wrow = wbase + ky * 7 * ws;
        #pragma unroll
        for (int kx = 0; kx < 7; kx++) {
            float4 wa = *reinterpret_cast<const float4*>(wrow + kx * ws);
            float4 wb = *reinterpret_cast<const float4*>(wrow + kx * ws + 4);
            #pragma unroll
            for (int o = 0; o < 4; o++) {
                bf16x8 v = rr[o + kx];
                acc[o][0] += bu2f((unsigned short)v[0]) * wa.x;
                acc[o][1] += bu2f((unsigned short)v[1]) * wa.y;
                acc[o][2] += bu2f((unsigned short)v[2]) * wa.z;
                acc[o][3] += bu2f((unsigned short)v[3]) * wa.w;
                acc[o][4] += bu2f((unsigned short)v[4]) * wb.x;
                acc[o][5] += bu2f((unsigned short)v[5]) * wb.y;
                acc[o][6] += bu2f((unsigned short)v[6]) * wb.z;
                acc[o][7] += bu2f((unsigned short)v[7]) * wb.w;
            }
        }
    }

    float4 ba = *reinterpret_cast<const float4*>(bp + cwt);
    float4 bb = *reinterpret_cast<const float4*>(bp + cwt + 4);
    bf16* obase = out + (size_t)b * HWSZ * 256 + ch0 + chg * 8;
    int gy = y0g + row;
    #pragma unroll
    for (int o = 0; o < 4; o++) {
        int gx = x0g + xg * 4 + o;
        bf16x8 ov;
        ov[0] = (short)f2bu(acc[o][0] + ba.x);
        ov[1] = (short)f2bu(acc[o][1] + ba.y);
        ov[2] = (short)f2bu(acc[o][2] + ba.z);
        ov[3] = (short)f2bu(acc[o][3] + ba.w);
        ov[4] = (short)f2bu(acc[o][4] + bb.x);
        ov[5] = (short)f2bu(acc[o][5] + bb.y);
        ov[6] = (short)f2bu(acc[o][6] + bb.z);
        ov[7] = (short)f2bu(acc[o][7] + bb.w);
        *reinterpret_cast<bf16x8*>(obase + ((size_t)gy * 56 + gx) * 256) = ov;
    }
}

// ---------------- rgb/t elementwise -> codin[N,256] ----------------
__global__ void rgbt_k(const bf16* __restrict__ rgb, const bf16* __restrict__ t,
                       bf16* __restrict__ codin, int total /* N*128 */)
{
    int i = blockIdx.x * blockDim.x + threadIdx.x;
    if (i >= total) return;
    int n = i >> 7, c = i & 127;
    float a = __bfloat162float(rgb[i]), bb = __bfloat162float(t[i]);
    codin[(size_t)n * 256 + c] = __float2bfloat16(a * bb);
    codin[(size_t)n * 256 + 128 + c] = __float2bfloat16(fabsf(a - bb));
}

// ---------------- cosine-gate partial reductions ----------------
__global__ __launch_bounds__(256) void cosred_k(const bf16* __restrict__ codi,
    float* __restrict__ part)   // [B][64][513]
{
    int b = blockIdx.x >> 4;
    int bi = blockIdx.x & 15;
    int wave = threadIdx.x >> 6, lane = threadIdx.x & 63;
    int slot = bi * 4 + wave;
    float dloc[4] = {0,0,0,0}, n2loc[4] = {0,0,0,0};
    float n1loc = 0.f;
    for (int i = 0; i < 49; i++) {
        int p = slot * 49 + i;
        const bf16* row = codi + ((size_t)b * HWSZ + p) * 256;
        float v[4]; float sum = 0.f;
        #pragma unroll
        for (int j = 0; j < 4; j++) { v[j] = __bfloat162float(row[lane + 64 * j]); sum += v[j]; }
        for (int off = 32; off; off >>= 1) sum += __shfl_xor(sum, off, 64);
        float amap = sum * (1.f / 256.f);
        #pragma unroll
        for (int j = 0; j < 4; j++) { dloc[j] += amap * v[j]; n2loc[j] += v[j] * v[j]; }
        n1loc += amap * amap;
    }
    float* dst = part + ((size_t)b * 64 + slot) * 513;
    #pragma unroll
    for (int j = 0; j < 4; j++) {
        dst[lane + 64 * j] = dloc[j];
        dst[256 + lane + 64 * j] = n2loc[j];
    }
    if (lane == 0) dst[512] = n1loc;
}

// ---------------- cos_sim + MLP + sigmoid -> attn_c[B,256] fp32 ----------------
__global__ __launch_bounds__(256) void mlp_kernel(const float* __restrict__ part,
    const float* __restrict__ fc1w, const float* __restrict__ fc2w,
    float* __restrict__ attnc)
{
    int b = blockIdx.x;
    int tid = threadIdx.x;
    __shared__ float cosb[256];
    __shared__ float hbuf[32];
    const float* pb = part + (size_t)b * 64 * 513;
    float dot = 0.f, n2 = 0.f, n1 = 0.f;
    for (int s = 0; s < 64; s++) {
        dot += pb[s * 513 + tid];
        n2  += pb[s * 513 + 256 + tid];
        n1  += pb[s * 513 + 512];
    }
    float cs = dot / (sqrtf(n1) * sqrtf(n2) + 1e-6f);
    cosb[tid] = cs;
    __syncthreads();
    if (tid < 32) {
        float h = 0.f;
        for (int c = 0; c < 256; c++) h += cosb[c] * fc1w[c * 32 + tid];
        h = 0.5f * h * (1.f + erff(h * 0.70710678f));
        hbuf[tid] = h;
    }
    __syncthreads();
    float o = 0.f;
    for (int j = 0; j < 32; j++) o += hbuf[j] * fc2w[j * 256 + tid];
    attnc[b * 256 + tid] = 1.f / (1.f + expf(-o));
}

// ---------------- 8x8 mean-pool of concat(xn, xen) -> rx_pool[B,49,384] fp32 ----------------
__global__ __launch_bounds__(384) void pool_kernel(const bf16* __restrict__ xn,
    const bf16* __restrict__ xen, float* __restrict__ rxpool)
{
    int bij = blockIdx.x;
    int b = bij / 49; int ij = bij % 49; int i = ij / 7, j = ij % 7;
    int c = threadIdx.x;
    float s = 0.f;
    for (int dy = 0; dy < 8; dy++)
        for (int dx = 0; dx < 8; dx++) {
            size_t n = ((size_t)b * 56 + (i * 8 + dy)) * 56 + (j * 8 + dx);
            s += (c < 256) ? __bfloat162float(xn[n * 256 + c])
                           : __bfloat162float(xen[n * 128 + (c - 256)]);
        }
    rxpool[(size_t)bij * 384 + c] = s * (1.f / 64.f);
}

// ---------------- MFMA flash attention over pooled q ----------------
// Grid: 128*NSPLIT blocks; bh = blk&127 (keeps all splits of a head on one XCD),
// split = blk>>7. Block: 256 thr = 4 waves; wave w = q-tile w (rows 16w..16w+15, q<49).
// Per 32-pos block: S^T = K·Q^T via 2 mfma (16-pos chunks, d padded 16->32),
// online softmax fully in-register (each lane owns q=lane&15's P for pos 8*hi..8*hi+7),
// P feeds PV mfma A-operand directly (C-layout == A-layout under pos remap
// 8*(x>>2)+(x&3)); V read transposed [bh][d][pos] -> contiguous 16B B-frag.
#define NSPLIT 14
#define POSB   224   // 3136/14, multiple of 32
__global__ __launch_bounds__(256) void attn_mfma(const float* __restrict__ qbuf,
    const bf16* __restrict__ kbuf, const bf16* __restrict__ vtbuf,
    float* __restrict__ osplit, float* __restrict__ mlbuf)
{
    int bh = blockIdx.x & 127;
    int split = blockIdx.x >> 7;
    int b = bh >> 3, h = bh & 7;
    int tid = threadIdx.x;
    int qt = tid >> 6;
    int lane = tid & 63;
    int lo = lane & 15, hi = lane >> 4;

    // Q fragment (B-operand): Q[q=qt*16+lo][d=8*hi+j], hi<2 real, scaled by hd^-0.5
    bf16x8 qf = {0, 0, 0, 0, 0, 0, 0, 0};
    int q = qt * 16 + lo;
    if (hi < 2 && q < 49) {
        const float* qp = qbuf + ((size_t)b * 49 + q) * 128 + h * 16 + hi * 8;
        #pragma unroll
        for (int j = 0; j < 8; j++) qf[j] = (short)f2bu(qp[j] * 0.25f);
    }
    const bf16* kbase = kbuf + (size_t)bh * HWSZ * 16;
    const bf16* vbase = vtbuf + ((size_t)bh * 16 + lo) * HWSZ;

    float m_run = -1e30f, l_run = 0.f;
    f32x4 oacc = {0.f, 0.f, 0.f, 0.f};
    int pos1 = 8 * (lo >> 2) + (lo & 3);   // chunk1 row->pos map within 32-block
    const f32x4 zz = {0.f, 0.f, 0.f, 0.f};

    for (int t = 0; t < POSB / 32; t++) {
        int base = split * POSB + t * 32;
        bf16x8 kf1 = {0, 0, 0, 0, 0, 0, 0, 0}, kf2 = kf1;
        if (hi < 2) {
            kf1 = *reinterpret_cast<const bf16x8*>(kbase + (size_t)(base + pos1) * 16 + hi * 8);
            kf2 = *reinterpret_cast<const bf16x8*>(kbase + (size_t)(base + pos1 + 4) * 16 + hi * 8);
        }
        bf16x8 vf = *reinterpret_cast<const bf16x8*>(vbase + base + hi * 8);
        // S^T tiles: lane holds S[pos=base+8*hi+r][q=qt*16+lo] in s1[r] (r<4), s2[r] (+4)
        f32x4 s1 = __builtin_amdgcn_mfma_f32_16x16x32_bf16(kf1, qf, zz, 0, 0, 0);
        f32x4 s2 = __builtin_amdgcn_mfma_f32_16x16x32_bf16(kf2, qf, zz, 0, 0, 0);
        // row(q) max: in-lane over 8, then across hi groups
        float pmax = fmaxf(fmaxf(fmaxf(s1[0], s1[1]), fmaxf(s1[2], s1[3])),
                           fmaxf(fmaxf(s2[0], s2[1]), fmaxf(s2[2], s2[3])));
        pmax = fmaxf(pmax, __shfl_xor(pmax, 16, 64));
        pmax = fmaxf(pmax, __shfl_xor(pmax, 32, 64));
        float mnew = fmaxf(m_run, pmax);
        float esc = __expf(m_run - mnew);
        l_run *= esc;
        // rescale O (O rows are q=4*hi+r; esc lives at lane lo=q)
        float e0 = __shfl(esc, 4 * hi + 0, 64);
        float e1 = __shfl(esc, 4 * hi + 1, 64);
        float e2 = __shfl(esc, 4 * hi + 2, 64);
        float e3 = __shfl(esc, 4 * hi + 3, 64);
        oacc[0] *= e0; oacc[1] *= e1; oacc[2] *= e2; oacc[3] *= e3;
        float p0 = __expf(s1[0] - mnew), p1 = __expf(s1[1] - mnew);
        float p2 = __expf(s1[2] - mnew), p3 = __expf(s1[3] - mnew);
        float p4 = __expf(s2[0] - mnew), p5 = __expf(s2[1] - mnew);
        float p6 = __expf(s2[2] - mnew), p7 = __expf(s2[3] - mnew);
        float rs = ((p0 + p1) + (p2 + p3)) + ((p4 + p5) + (p6 + p7));
        rs += __shfl_xor(rs, 16, 64);
        rs += __shfl_xor(rs, 32, 64);
        l_run += rs;
        m_run = mnew;
        bf16x8 pf;
        pf[0] = (short)f2bu(p0); pf[1] = (short)f2bu(p1);
        pf[2] = (short)f2bu(p2); pf[3] = (short)f2bu(p3);
        pf[4] = (short)f2bu(p4); pf[5] = (short)f2bu(p5);
        pf[6] = (short)f2bu(p6); pf[7] = (short)f2bu(p7);
        oacc = __builtin_amdgcn_mfma_f32_16x16x32_bf16(pf, vf, oacc, 0, 0, 0);
    }

    // store partial O (rows q=qt*16+4*hi+r, col d=lo) + per-q (m,l)
    float* ob = osplit + ((size_t)bh * NSPLIT + split) * 64 * 16;
    #pragma unroll
    for (int r = 0; r < 4; r++) {
        int qq = qt * 16 + 4 * hi + r;
        ob[(size_t)qq * 16 + lo] = oacc[r];
    }
    if (hi == 0) {
        float* mlb = mlbuf + (((size_t)bh * NSPLIT + split) * 64 + qt * 16 + lo) * 2;
        mlb[0] = m_run; mlb[1] = l_run;
    }
}

// ---------------- merge split partials -> gs[bh][49][16] ----------------
__global__ __launch_bounds__(256) void attn_combine(const float* __restrict__ osplit,
    const float* __restrict__ mlbuf, float* __restrict__ gs)
{
    int idx = blockIdx.x * 256 + threadIdx.x;   // over 128*49*16
    if (idx >= 128 * 49 * 16) return;
    int d = idx & 15;
    int pq = idx >> 4;
    int bh = pq / 49, q = pq % 49;
    float m[NSPLIT], l[NSPLIT];
    float M = -1e30f;
    #pragma unroll
    for (int s = 0; s < NSPLIT; s++) {
        const float* mlb = mlbuf + (((size_t)bh * NSPLIT + s) * 64 + q) * 2;
        m[s] = mlb[0]; l[s] = mlb[1];
        M = fmaxf(M, m[s]);
    }
    float L = 0.f, O = 0.f;
    #pragma unroll
    for (int s = 0; s < NSPLIT; s++) {
        float e = __expf(m[s] - M);
        L += l[s] * e;
        O += osplit[(((size_t)bh * NSPLIT + s) * 64 + q) * 16 + d] * e;
    }
    gs[(size_t)pq * 16 + d] = O / L;
}

// ---------------- bilinear 7->56 upsample into cat[:, 384:512] ----------------
__global__ void upsample_kernel(const float* __restrict__ gs, bf16* __restrict__ cat)
{
    int idx = blockIdx.x * blockDim.x + threadIdx.x;  // over N*128
    if (idx >= N_TOK * 128) return;
    int c = idx & 127;
    int pos = idx >> 7;
    int h = c >> 4, d = c & 15;
    int x = pos % 56;
    int y = (pos / 56) % 56;
    int b = pos / HWSZ;
    float sy = (y + 0.5f) * 0.125f - 0.5f;
    float sx = (x + 0.5f) * 0.125f - 0.5f;
    int y0f = (int)floorf(sy); float wy = sy - (float)y0f;
    int x0f = (int)floorf(sx); float wx = sx - (float)x0f;
    int y0 = max(0, min(6, y0f)), y1 = max(0, min(6, y0f + 1));
    int x0 = max(0, min(6, x0f)), x1 = max(0, min(6, x0f + 1));
    const float* g0 = gs + ((size_t)(b * 8 + h) * 49) * 16 + d;
    float v00 = g0[(y0 * 7 + x0) * 16], v01 = g0[(y0 * 7 + x1) * 16];
    float v10 = g0[(y1 * 7 + x0) * 16], v11 = g0[(y1 * 7 + x1) * 16];
    float v0 = v00 + (v01 - v00) * wx;
    float v1 = v10 + (v11 - v10) * wx;
    float v = v0 + (v1 - v0) * wy;
    cat[(size_t)pos * 512 + 384 + c] = __float2bfloat16(v);
}

extern "C" void kernel_launch(void* const* d_in, const int* in_sizes, int n_in,
                              void* d_out, int out_size, void* d_ws, size_t ws_size,
                              hipStream_t stream)
{
    const float* x      = (const float*)d_in[0];
    const float* x_e    = (const float*)d_in[1];
    const float* norm_w = (const float*)d_in[2];
    const float* norm_b = (const float*)d_in[3];
    const float* norme_w= (const float*)d_in[4];
    const float* norme_b= (const float*)d_in[5];
    const float* rr1_w  = (const float*)d_in[6];
    const float* rr1_b  = (const float*)d_in[7];
    const float* rr2_w  = (const float*)d_in[8];
    const float* rr2_b  = (const float*)d_in[9];
    const float* rr3_w  = (const float*)d_in[10];
    const float* rr3_b  = (const float*)d_in[11];
    const float* conv_w = (const float*)d_in[12];
    const float* conv_b = (const float*)d_in[13];
    const float* l1_w   = (const float*)d_in[14];
    const float* l1_b   = (const float*)d_in[15];
    const float* l2_w   = (const float*)d_in[16];
    const float* l2_b   = (const float*)d_in[17];
    const float* c1_w   = (const float*)d_in[18];
    const float* c1_b   = (const float*)d_in[19];
    const float* c2_w   = (const float*)d_in[20];
    const float* c2_b   = (const float*)d_in[21];
    const float* fc1_w  = (const float*)d_in[22];
    const float* fc2_w  = (const float*)d_in[23];
    const float* l3_w   = (const float*)d_in[24];
    const float* l3_b   = (const float*)d_in[25];
    const float* kv_w   = (const float*)d_in[26];
    const float* kv_b   = (const float*)d_in[27];
    const float* q_w    = (const float*)d_in[28];
    const float* q_b    = (const float*)d_in[29];
    const float* proj_w = (const float*)d_in[30];
    const float* proj_b = (const float*)d_in[31];
    const float* proje_w= (const float*)d_in[32];
    const float* proje_b= (const float*)d_in[33];

    // ---- workspace: fp32 smalls, bf16 transposed weights, bf16 slabs ----
    float* part   = (float*)d_ws;                 // 16*64*513
    float* attnc  = part   + (size_t)525312;      // 16*256
    float* gs     = attnc  + 4096;                // 16*8*49*16
    float* rxpool = gs     + 100352;              // 784*384
    float* qbuf   = rxpool + 301056;              // 784*128
    bf16* wt      = (bf16*)(qbuf + 100352);
    bf16* rr1_t  = wt;              // 256x256
    bf16* rr2_t  = rr1_t + 65536;
    bf16* rr3_t  = rr2_t + 65536;
    bf16* kv_t   = rr3_t + 65536;
    bf16* l1_t   = kv_t  + 65536;   // 128x256
    bf16* l2_t   = l1_t  + 32768;   // 128x128
    bf16* l3_t   = l2_t  + 16384;   // 128x256
    bf16* proj_t = l3_t  + 32768;   // 256x512
    bf16* proje_t= proj_t + 131072; // 128x512
    bf16* xn     = proje_t + 65536;
    bf16* xen    = xn   + (size_t)N_TOK * 256;
    bf16* bufC   = xen  + (size_t)N_TOK * 128;   // rr1 / codin / K|V head-major
    bf16* bufD   = bufC + (size_t)N_TOK * 256;   // rr2pre / rgb|t / attn partials
    bf16* bufE   = bufD + (size_t)N_TOK * 256;   // conv out / co_di
    bf16* cat    = bufE + (size_t)N_TOK * 256;   // [N,512]
    size_t need = (size_t)((char*)(cat + (size_t)N_TOK * 512) - (char*)d_ws);
    if (ws_size < need) return;

    bf16* kbuf = bufC;                       // [B*8][HWSZ][16]
    bf16* vbuf = bufC + (size_t)N_TOK * 128; // [B*8][16][HWSZ] (transposed)

    // attn split partials live in bufD (free during phase 4): 8.26 MB
    float* osplit = (float*)bufD;                          // [128][NSPLIT][64][16]
    float* mlbuf  = osplit + (size_t)128 * NSPLIT * 64 * 16; // [128][NSPLIT][64][2]

    float* xout  = (float*)d_out;
    float* xeout = xout + (size_t)N_TOK * 256;

    const int nthr = 256;
    auto mgrid = [](int M, int N) { return dim3((M / 128) * (N / 128)); };

    // 0. weight prep (one launch)
    {
        WtrPack p;
        const float* srcs[9] = {rr1_w, rr2_w, rr3_w, kv_w, l1_w, l2_w, l3_w, proj_w, proje_w};
        bf16* dsts[9] = {rr1_t, rr2_t, rr3_t, kv_t, l1_t, l2_t, l3_t, proj_t, proje_t};
        int Ks[9] = {256, 256, 256, 256, 256, 128, 256, 512, 512};
        int Ns[9] = {256, 256, 256, 256, 128, 128, 128, 256, 128};
        int off = 0;
        for (int s = 0; s < 9; s++) {
            p.d[s] = {srcs[s], dsts[s], Ks[s], Ns[s], off};
            off += Ks[s] * Ns[s];
        }
        p.total = off;
        wtr_all<<<dim3((off + 255) / 256), dim3(256), 0, stream>>>(p);
    }

    // 1. LayerNorms
    ln_kernel<<<dim3(N_TOK / 4), dim3(nthr), 0, stream>>>(x, norm_w, norm_b, xn, N_TOK, 256);
    ln_kernel<<<dim3(N_TOK / 4), dim3(nthr), 0, stream>>>(x_e, norme_w, norme_b, xen, N_TOK, 128);

    // 2. local_rr -> cat[:, 0:256]
    gemm_mfma<0, bf16><<<mgrid(N_TOK, 256), dim3(nthr), 0, stream>>>(
        xn, 256, rr1_t, rr1_b, bufC, 256, N_TOK, 256, 256, nullptr, 0, nullptr, nullptr, nullptr);
    gemm_mfma<0, bf16><<<mgrid(N_TOK, 256), dim3(nthr), 0, stream>>>(
        xn, 256, rr2_t, rr2_b, bufD, 256, N_TOK, 256, 256, nullptr, 0, nullptr, nullptr, nullptr);
    dwconv_tile<<<dim3(BATCH * 56), dim3(448), 0, stream>>>(
        bufD, bufE, conv_w, conv_b, conv_w, conv_b, 256);
    gemm_mfma<GF_MUL, bf16><<<mgrid(N_TOK, 256), dim3(nthr), 0, stream>>>(
        bufE, 256, rr3_t, rr3_b, cat, 512, N_TOK, 256, 256, bufC, 256, nullptr, nullptr, nullptr);

    // 3. LocalAttentionRGBT -> cat[:, 256:384]
    gemm_mfma<0, bf16><<<mgrid(N_TOK, 128), dim3(nthr), 0, stream>>>(
        xn, 256, l1_t, l1_b, bufD, 128, N_TOK, 256, 128, nullptr, 0, nullptr, nullptr, nullptr);
    gemm_mfma<0, bf16><<<mgrid(N_TOK, 128), dim3(nthr), 0, stream>>>(
        xen, 128, l2_t, l2_b, bufD + (size_t)N_TOK * 128, 128, N_TOK, 128, 128, nullptr, 0, nullptr, nullptr, nullptr);
    rgbt_k<<<dim3((N_TOK * 128) / nthr), dim3(nthr), 0, stream>>>(
        bufD, bufD + (size_t)N_TOK * 128, bufC, N_TOK * 128);
    dwconv_tile<<<dim3(BATCH * 56), dim3(448), 0, stream>>>(
        bufC, bufE, c1_w, c1_b, c2_w, c2_b, 128);
    cosred_k<<<dim3(BATCH * 16), dim3(nthr), 0, stream>>>(bufE, part);
    mlp_kernel<<<dim3(BATCH), dim3(nthr), 0, stream>>>(part, fc1_w, fc2_w, attnc);
    gemm_mfma<GF_ASCALE, bf16><<<mgrid(N_TOK, 128), dim3(nthr), 0, stream>>>(
        bufE, 256, l3_t, l3_b, cat + 256, 512, N_TOK, 256, 128, nullptr, 0, attnc, nullptr, nullptr);

    // 4. global pooled attention -> cat[:, 384:512]
    gemm_mfma<GF_KVSPLIT, bf16><<<mgrid(N_TOK, 256), dim3(nthr), 0, stream>>>(
        xn, 256, kv_t, kv_b, (bf16*)nullptr, 0, N_TOK, 256, 256, nullptr, 0, nullptr, kbuf, vbuf);
    pool_kernel<<<dim3(BATCH * 49), dim3(384), 0, stream>>>(xn, xen, rxpool);
    gemm_k<<<dim3(((784 + 63) / 64) * 2), dim3(nthr), 0, stream>>>(
        rxpool, 384, q_w, q_b, qbuf, 128, 784, 384, 128);
    attn_mfma<<<dim3(128 * NSPLIT), dim3(nthr), 0, stream>>>(qbuf, kbuf, vbuf, osplit, mlbuf);
    attn_combine<<<dim3(392), dim3(nthr), 0, stream>>>(osplit, mlbuf, gs);
    upsample_kernel<<<dim3((N_TOK * 128) / nthr), dim3(nthr), 0, stream>>>(gs, cat);

    // 5. output projections (fp32 out)
    gemm_mfma<0, float><<<mgrid(N_TOK, 256), dim3(nthr), 0, stream>>>(
        cat, 512, proj_t, proj_b, xout, 256, N_TOK, 512, 256, nullptr, 0, nullptr, nullptr, nullptr);
    gemm_mfma<0, float><<<mgrid(N_TOK, 128), dim3(nthr), 0, stream>>>(
        cat, 512, proje_t, proje_b, xeout, 128, N_TOK, 512, 128, nullptr, 0, nullptr, nullptr, nullptr);
}